// Round 6
// baseline (354.268 us; speedup 1.0000x reference)
//
#include <hip/hip_runtime.h>
#include <cstddef>

#define HWO 16384   // 128*128
#define CTOT 1536

typedef __attribute__((ext_vector_type(8))) short bf16x8;
typedef __attribute__((ext_vector_type(4))) float f32x4;

__device__ inline unsigned short f2bf(float x) {
  union { float f; unsigned u; } v; v.f = x;
  unsigned r = v.u + 0x7FFFu + ((v.u >> 16) & 1u);
  return (unsigned short)(r >> 16);
}
__device__ inline float bf2f(unsigned short h) {
  union { unsigned u; float f; } v; v.u = ((unsigned)h) << 16; return v.f;
}

struct __align__(16) Prm { unsigned short i00, i01, i10, i11; float wx, wy; };

// ---------------------------------------------------------------------------
// Setup: 7 weight transposes + BN fold + mc1 + fuse_w LDS-tiled transpose.
// ---------------------------------------------------------------------------
struct SetupArgs {
  const float* W[7];
  unsigned short* T[7];
  int K[7], N[7], bstart[8];
  const float *bn_g, *bn_v, *bn_m, *bn_b;
  float *sc, *sh;
  const float* c1;
  float* mc1;                 // [2*96]
  const float* fw;            // fuse_w [1536][384]
  unsigned short* fwt;        // [384][1536] bf16
  int nTP;
};
__global__ __launch_bounds__(256) void setup_kernel(SetupArgs a) {
  int bid = blockIdx.x;
  if (bid < a.nTP) {
    int s = 0;
#pragma unroll
    for (int i = 1; i < 7; i++) if (bid >= a.bstart[i]) s = i;
    const int K = a.K[s], N = a.N[s];
    const int idx = (bid - a.bstart[s]) * 256 + threadIdx.x;
    if (idx >= K * N) return;
    const int k = idx / N, o = idx - k * N;
    a.T[s][(size_t)o * K + k] = f2bf(a.W[s][idx]);
    return;
  }
  bid -= a.nTP;
  if (bid < 2) {   // BN fold
    const int o = bid * 256 + threadIdx.x;
    if (o < 384) {
      const float sc = a.bn_g[o] * rsqrtf(a.bn_v[o] + 1e-5f);
      a.sc[o] = sc;
      a.sh[o] = a.bn_b[o] - a.bn_m[o] * sc;
    }
    return;
  }
  bid -= 2;
  if (bid < 192) {  // mc1: one block per (b*96+ch)
    const float4* p = (const float4*)(a.c1 + (size_t)bid * HWO);
    float acc = 0.f;
    for (int i = threadIdx.x; i < HWO / 4; i += 256) {
      const float4 v = p[i];
      acc += (v.x + v.y) + (v.z + v.w);
    }
    for (int o = 32; o > 0; o >>= 1) acc += __shfl_down(acc, o, 64);
    __shared__ float red[4];
    if ((threadIdx.x & 63) == 0) red[threadIdx.x >> 6] = acc;
    __syncthreads();
    if (threadIdx.x == 0)
      a.mc1[bid] = (red[0] + red[1] + red[2] + red[3]) * (1.0f / HWO);
    return;
  }
  bid -= 192;       // fuse_w transpose: 48 k-tiles x 12 o-tiles (32x32)
  const int tk = bid / 12, to = bid % 12;
  __shared__ float tile[32][33];
  const int rr0 = threadIdx.x >> 5, cch = threadIdx.x & 31;
#pragma unroll
  for (int rr = rr0; rr < 32; rr += 8)
    tile[rr][cch] = a.fw[(size_t)(tk * 32 + rr) * 384 + to * 32 + cch];
  __syncthreads();
#pragma unroll
  for (int rr = rr0; rr < 32; rr += 8)
    a.fwt[(size_t)(to * 32 + rr) * 1536 + tk * 32 + cch] = f2bf(tile[cch][rr]);
}

// ---------------------------------------------------------------------------
// Position-major MFMA GEMM.
// XMODE 1: X bf16 [B][P][K]; XMODE 0: X f32 [B][K][P] (transpose in staging).
// OMODE 0: f32 +bias | 1: bf16 +bias | 2: bf16 BN+ReLU | 3: bf16 (r+b)*gate.
// ---------------------------------------------------------------------------
template<int K, int WM, int WN, int MT, int OT, int XMODE, int OMODE>
__global__ __launch_bounds__(WM * WN * 64) void pm_gemm(
    const void* __restrict__ Xv, const unsigned short* __restrict__ Wt,
    const float* __restrict__ bias, const float* __restrict__ ep_a,
    const float* __restrict__ ep_b, void* __restrict__ Yv,
    int P, long x_bs, long wt_bs, long y_bs, int yrs, int ycol, int ep_abs) {
  constexpr int BM = WM * MT * 16, BN = WN * OT * 16, NTH = WM * WN * 64;
  constexpr int BK = (K % 64 == 0) ? 64 : 32;
  constexpr int LST = BK + 8;
  static_assert(XMODE == 1 || BM == 128, "XMODE0 staging assumes BM=128");
  __shared__ unsigned short Alds[BM * LST];
  __shared__ unsigned short Blds[BN * LST];
  const int tid = threadIdx.x;
  const int w = tid >> 6, lane = tid & 63;
  const int wm = w / WN, wn = w % WN;
  const int b = blockIdx.z;
  const int p0 = blockIdx.x * BM;
  const int o0 = blockIdx.y * BN;
  const unsigned short* Wb = Wt + (long)b * wt_bs + (long)o0 * K;
  f32x4 acc[MT * OT];
#pragma unroll
  for (int i = 0; i < MT * OT; i++) acc[i] = (f32x4){0.f, 0.f, 0.f, 0.f};
  const int lr = lane & 15, lk = (lane >> 4) * 8;

  for (int kc = 0; kc < K; kc += BK) {
    if constexpr (XMODE == 1) {
      const unsigned short* Xb = (const unsigned short*)Xv + (long)b * x_bs;
#pragma unroll
      for (int it = 0; it < BM * (BK / 8) / NTH; it++) {
        const int idx = tid + it * NTH;
        const int r = idx / (BK / 8), ck = (idx % (BK / 8)) * 8;
        *(uint4*)&Alds[r * LST + ck] =
            *(const uint4*)(Xb + (long)(p0 + r) * K + kc + ck);
      }
    } else {
      const float* Xf = (const float*)Xv + (long)b * x_bs;
#pragma unroll
      for (int it = 0; it < BK * 32 / NTH; it++) {
        const int idx = tid + it * NTH;
        const int k = idx >> 5, pg = (idx & 31) * 4;
        const float4 v = *(const float4*)(Xf + (long)(kc + k) * P + p0 + pg);
        Alds[(pg + 0) * LST + k] = f2bf(v.x);
        Alds[(pg + 1) * LST + k] = f2bf(v.y);
        Alds[(pg + 2) * LST + k] = f2bf(v.z);
        Alds[(pg + 3) * LST + k] = f2bf(v.w);
      }
    }
#pragma unroll
    for (int it = 0; it < BN * (BK / 8) / NTH; it++) {
      const int idx = tid + it * NTH;
      const int r = idx / (BK / 8), ck = (idx % (BK / 8)) * 8;
      *(uint4*)&Blds[r * LST + ck] =
          *(const uint4*)(Wb + (long)r * K + kc + ck);
    }
    __syncthreads();
#pragma unroll
    for (int kk = 0; kk < BK; kk += 32) {
      bf16x8 af[MT];
#pragma unroll
      for (int mt = 0; mt < MT; mt++)
        af[mt] = *(const bf16x8*)&Alds[((wm * MT + mt) * 16 + lr) * LST + kk + lk];
#pragma unroll
      for (int ot = 0; ot < OT; ot++) {
        const bf16x8 bfr =
            *(const bf16x8*)&Blds[((wn * OT + ot) * 16 + lr) * LST + kk + lk];
#pragma unroll
        for (int mt = 0; mt < MT; mt++)
          acc[mt * OT + ot] = __builtin_amdgcn_mfma_f32_16x16x32_bf16(
              af[mt], bfr, acc[mt * OT + ot], 0, 0, 0);
      }
    }
    __syncthreads();
  }
  const int r0 = (lane >> 4) * 4;
#pragma unroll
  for (int mt = 0; mt < MT; mt++) {
#pragma unroll
    for (int ot = 0; ot < OT; ot++) {
      const int o = o0 + (wn * OT + ot) * 16 + lr;
      const f32x4 r = acc[mt * OT + ot];
      const float bv = bias ? bias[o] : 0.f;
      float sa = 0.f, sb = 0.f;
      if constexpr (OMODE == 2) { sa = ep_a[o]; sb = ep_b[o]; }
      if constexpr (OMODE == 3) { sa = ep_a[(long)b * ep_abs + o]; }
#pragma unroll
      for (int jj = 0; jj < 4; jj++) {
        const long row = p0 + (wm * MT + mt) * 16 + r0 + jj;
        float v = r[jj] + bv;
        if constexpr (OMODE == 2) v = fmaxf(fmaf(v, sa, sb), 0.f);
        if constexpr (OMODE == 3) v = v * sa;
        if constexpr (OMODE == 0)
          ((float*)Yv)[(long)b * y_bs + row * yrs + ycol + o] = v;
        else
          ((unsigned short*)Yv)[(long)b * y_bs + row * yrs + ycol + o] = f2bf(v);
      }
    }
  }
}

// ---------------------------------------------------------------------------
// Bilinear sampling params per (b, g'=lvl*4+g, output pixel).
// ---------------------------------------------------------------------------
__global__ __launch_bounds__(256) void params_kernel(
    const float* __restrict__ bo4, const float* __restrict__ bo3,
    const float* __restrict__ bo2, Prm* __restrict__ prm) {
  const int gp = blockIdx.y, b = blockIdx.z;
  const int p = blockIdx.x * 256 + threadIdx.x;
  const int lvl = gp >> 2, g = gp & 3;
  const float* bo; int ls, H, offC;
  if (lvl == 0)      { bo = bo4; ls = 3; H = 16; offC = 512; }
  else if (lvl == 1) { bo = bo3; ls = 2; H = 32; offC = 128; }
  else               { bo = bo2; ls = 1; H = 64; offC = 32; }
  const int s = 1 << ls, ss = s * s, W = H, HWs = H * H;
  const int yo = p >> 7, xo = p & 127;
  const int h = yo >> ls, i = yo & (s - 1);
  const int w = xo >> ls, j = xo & (s - 1);
  const int sp = h * W + w;
  const float* offp = bo + ((size_t)b * HWs + sp) * offC;
  const float cx = offp[g * ss + i * s + j];
  const float cy = offp[(4 + g) * ss + i * s + j];
  const float inv_s = 1.0f / (float)s;
  const float offx = cx * 0.25f + ((float)j - (s - 1) * 0.5f) * inv_s;
  const float offy = cy * 0.25f + ((float)i - (s - 1) * 0.5f) * inv_s;
  float xf = fminf(fmaxf((float)w + offx, 0.0f), (float)(W - 1));
  float yf = fminf(fmaxf((float)h + offy, 0.0f), (float)(H - 1));
  const float x0f = floorf(xf), y0f = floorf(yf);
  const int x0 = (int)x0f, y0 = (int)y0f;
  const int x1 = min(x0 + 1, W - 1), y1 = min(y0 + 1, H - 1);
  Prm pr;
  pr.i00 = (unsigned short)(y0 * W + x0);
  pr.i01 = (unsigned short)(y0 * W + x1);
  pr.i10 = (unsigned short)(y1 * W + x0);
  pr.i11 = (unsigned short)(y1 * W + x1);
  pr.wx = xf - x0f;
  pr.wy = yf - y0f;
  prm[((size_t)b * 12 + gp) * HWO + p] = pr;
}

// ---------------------------------------------------------------------------
// Per-channel sums of the virtual upsampled maps -> partials.
// ---------------------------------------------------------------------------
__global__ __launch_bounds__(256) void mean_up(
    const unsigned short* __restrict__ bp4, const unsigned short* __restrict__ bp3,
    const unsigned short* __restrict__ bp2, const Prm* __restrict__ prm,
    float* __restrict__ part) {
  const int gp = blockIdx.y, b = blockIdx.z;
  const int lvl = gp >> 2, g = gp & 3;
  const unsigned short* bpL; int HWs_;
  if (lvl == 0)      { bpL = bp4; HWs_ = 256; }
  else if (lvl == 1) { bpL = bp3; HWs_ = 1024; }
  else               { bpL = bp2; HWs_ = 4096; }
  const int tid = threadIdx.x;
  const int chunk = tid % 12, pl = tid / 12;
  float acc[8];
#pragma unroll
  for (int j = 0; j < 8; j++) acc[j] = 0.f;
  const Prm* pp = prm + ((size_t)b * 12 + gp) * HWO + blockIdx.x * 512;
  const unsigned short* qb = bpL + (size_t)b * HWs_ * 384 + g * 96 + chunk * 8;
  if (tid < 252) {
    for (int it = 0; it < 25; it++) {
      const int pli = it * 21 + pl;
      if (pli < 512) {
        const Prm pr = pp[pli];
        const float wx = pr.wx, wy = pr.wy;
        const float w00 = (1.f - wx) * (1.f - wy), w01 = wx * (1.f - wy);
        const float w10 = (1.f - wx) * wy, w11 = wx * wy;
        const uint4 v00 = *(const uint4*)(qb + (size_t)pr.i00 * 384);
        const uint4 v01 = *(const uint4*)(qb + (size_t)pr.i01 * 384);
        const uint4 v10 = *(const uint4*)(qb + (size_t)pr.i10 * 384);
        const uint4 v11 = *(const uint4*)(qb + (size_t)pr.i11 * 384);
        const unsigned short* s00 = (const unsigned short*)&v00;
        const unsigned short* s01 = (const unsigned short*)&v01;
        const unsigned short* s10 = (const unsigned short*)&v10;
        const unsigned short* s11 = (const unsigned short*)&v11;
#pragma unroll
        for (int j = 0; j < 8; j++)
          acc[j] += w00 * bf2f(s00[j]) + w01 * bf2f(s01[j]) +
                    w10 * bf2f(s10[j]) + w11 * bf2f(s11[j]);
      }
    }
  }
  __shared__ float red[12][8][22];
  if (tid < 252) {
#pragma unroll
    for (int j = 0; j < 8; j++) red[chunk][j][pl] = acc[j];
  }
  __syncthreads();
  if (tid < 96) {
    float s = 0.f;
#pragma unroll
    for (int l = 0; l < 21; l++) s += red[tid >> 3][tid & 7][l];
    part[((size_t)blockIdx.x * 2 + b) * 1152 + gp * 96 + tid] = s;
  }
}

// ---------------------------------------------------------------------------
// SSM prep (mean from partials or mc1 path).
// ---------------------------------------------------------------------------
__global__ __launch_bounds__(64) void ssm_prep(
    const float* __restrict__ part, const float* __restrict__ mc1,
    const float* __restrict__ mlp1_w, const float* __restrict__ mlp1_b,
    const float* __restrict__ in_w, const float* __restrict__ in_b,
    const float* __restrict__ xproj_w, const float* __restrict__ dt_w,
    const float* __restrict__ dt_b, float* __restrict__ u_out,
    float2* __restrict__ dtdu_out, float* __restrict__ Bs_out,
    float* __restrict__ Cs_out) {
  const int bc = blockIdx.x;
  const int b = bc / 1536, c = bc - b * 1536;
  const int d = threadIdx.x;
  float sv;
  if (c < 1152) {
    float a = (d < 32) ? part[((size_t)d * 2 + b) * 1152 + c] : 0.f;
    a += __shfl_xor(a, 1, 64);  a += __shfl_xor(a, 2, 64);
    a += __shfl_xor(a, 4, 64);  a += __shfl_xor(a, 8, 64);
    a += __shfl_xor(a, 16, 64); a += __shfl_xor(a, 32, 64);
    sv = a * (1.0f / HWO);
  } else {
    const int c2 = c - 1152;
    float a = mc1[b * 96 + d] * mlp1_w[d * 384 + c2];
    if (d < 32) a += mc1[b * 96 + 64 + d] * mlp1_w[(64 + d) * 384 + c2];
    a += __shfl_xor(a, 1, 64);  a += __shfl_xor(a, 2, 64);
    a += __shfl_xor(a, 4, 64);  a += __shfl_xor(a, 8, 64);
    a += __shfl_xor(a, 16, 64); a += __shfl_xor(a, 32, 64);
    sv = a + mlp1_b[c2];
  }
  const float u = sv * in_w[d] + in_b[d];
  __shared__ float ush[64];
  __shared__ float proj[33];
  ush[d] = u;
  __syncthreads();
  if (d < 33) {
    float acc = 0.f;
    for (int k = 0; k < 64; k++) acc = fmaf(ush[k], xproj_w[k * 33 + d], acc);
    proj[d] = acc;
  }
  __syncthreads();
  float dtv = proj[0] * dt_w[d] + dt_b[d];
  dtv = (dtv > 20.0f) ? dtv : log1pf(__expf(dtv));   // softplus
  u_out[(size_t)bc * 64 + d] = u;
  dtdu_out[(size_t)bc * 64 + d] = make_float2(dtv, dtv * u);
  if (d < 16) {
    Bs_out[(size_t)bc * 16 + d] = proj[1 + d];
    Cs_out[(size_t)bc * 16 + d] = proj[17 + d];
  }
}

// ---------------------------------------------------------------------------
// Parallel associative scan. grid = (64 d, 2 dir, 2 b), block 256.
// ---------------------------------------------------------------------------
__global__ __launch_bounds__(256) void ssm_scan_par(
    const float2* __restrict__ dtdu, const float* __restrict__ Bs,
    const float* __restrict__ Cs, const float* __restrict__ A_log,
    float* __restrict__ y) {
  const int d = blockIdx.x, dir = blockIdx.y, b = blockIdx.z;
  const int t = threadIdx.x;
  const int j = t >> 4, n = t & 15;
  const float A = -__expf(A_log[d * 16 + n]);
  const int s0 = j * 96;
  const int c0 = dir ? (1535 - s0) : s0;
  const int step = dir ? -1 : 1;
  const float2* dbase = dtdu + (size_t)b * 1536 * 64 + (size_t)c0 * 64 + d;
  const float* bbase = Bs + (size_t)b * 1536 * 16 + (size_t)c0 * 16 + n;
  const float* cbase = Cs + (size_t)b * 1536 * 16 + (size_t)c0 * 16 + n;
  const long dstep = (long)step * 64;
  const long bstep = (long)step * 16;

  float Ap = 1.f, Bp = 0.f;
  {
    const float2* dp = dbase;
    const float* bp = bbase;
    float2 td = *dp;
    float Bv = *bp;
    for (int i = 0; i < 96; i++) {
      const float2 tdc = td;
      const float Bc = Bv;
      dp += dstep; bp += bstep;
      if (i + 1 < 96) { td = *dp; Bv = *bp; }
      const float a = __expf(tdc.x * A);
      Bp = fmaf(a, Bp, tdc.y * Bc);
      Ap *= a;
    }
  }
  __shared__ float sA[16][16], sB[16][16];
  sA[j][n] = Ap;
  sB[j][n] = Bp;
  __syncthreads();
  float H = 0.f;
  for (int jj = 0; jj < j; jj++) H = fmaf(sA[jj][n], H, sB[jj][n]);

  float* yb = y + (size_t)(b * 2 + dir) * 1536 * 64;
  {
    const float2* dp = dbase;
    const float* bp = bbase;
    const float* cp = cbase;
    float2 td = *dp;
    float Bv = *bp;
    float Cv = *cp;
    float h = H;
    int c = c0;
    for (int i = 0; i < 96; i++) {
      const float2 tdc = td;
      const float Bc = Bv, Cc = Cv;
      dp += dstep; bp += bstep; cp += bstep;
      if (i + 1 < 96) { td = *dp; Bv = *bp; Cv = *cp; }
      const float a = __expf(tdc.x * A);
      h = fmaf(a, h, tdc.y * Bc);
      float pr = h * Cc;
      pr += __shfl_xor(pr, 1, 64);
      pr += __shfl_xor(pr, 2, 64);
      pr += __shfl_xor(pr, 4, 64);
      pr += __shfl_xor(pr, 8, 64);
      if (n == 0) yb[(size_t)c * 64 + d] = pr;
      c += step;
    }
  }
}

// ---------------------------------------------------------------------------
// Gate.
// ---------------------------------------------------------------------------
__global__ __launch_bounds__(64) void gate_kernel(
    const float* __restrict__ y, const float* __restrict__ u,
    const float* __restrict__ Dp, const float* __restrict__ out_w,
    const float* __restrict__ out_b, float* __restrict__ gate) {
  const int c = blockIdx.x, b = blockIdx.y, d = threadIdx.x;
  const size_t i = ((size_t)b * 1536 + c) * 64 + d;
  float yt = y[((size_t)(b * 2) * 1536 + c) * 64 + d]
           + y[((size_t)(b * 2 + 1) * 1536 + c) * 64 + d]
           + Dp[d] * u[i];
  float v = yt * out_w[d];
  for (int o = 32; o > 0; o >>= 1) v += __shfl_down(v, o, 64);
  if (d == 0) gate[b * 1536 + c] = 1.0f / (1.0f + __expf(-(v + out_b[0])));
}

// ---------------------------------------------------------------------------
// Materialize gated cc cols 0..1152: bilinear gather x gate -> bf16 [p][1536].
// grid (128 pos-blocks, 12 gp, 2 b), block 256 = 128 pos x 2 halves.
// ---------------------------------------------------------------------------
__global__ __launch_bounds__(256) void cc_mat(
    const unsigned short* __restrict__ bp4, const unsigned short* __restrict__ bp3,
    const unsigned short* __restrict__ bp2, const Prm* __restrict__ prm,
    const float* __restrict__ gate, unsigned short* __restrict__ ccg) {
  const int gp = blockIdx.y, b = blockIdx.z;
  const int lvl = gp >> 2, g = gp & 3;
  const unsigned short* bpL; int HWs_;
  if (lvl == 0)      { bpL = bp4; HWs_ = 256; }
  else if (lvl == 1) { bpL = bp3; HWs_ = 1024; }
  else               { bpL = bp2; HWs_ = 4096; }
  __shared__ float gsh[96];
  if (threadIdx.x < 96)
    gsh[threadIdx.x] = gate[b * 1536 + gp * 96 + threadIdx.x];
  __syncthreads();
  const int pos = threadIdx.x >> 1, half = threadIdx.x & 1;
  const int p = blockIdx.x * 128 + pos;
  const Prm pr = prm[((size_t)b * 12 + gp) * HWO + p];
  const float wx = pr.wx, wy = pr.wy;
  const float w00 = (1.f - wx) * (1.f - wy), w01 = wx * (1.f - wy);
  const float w10 = (1.f - wx) * wy, w11 = wx * wy;
  const unsigned short* qb = bpL + (size_t)b * HWs_ * 384 + g * 96 + half * 48;
  const unsigned short* q00 = qb + (size_t)pr.i00 * 384;
  const unsigned short* q01 = qb + (size_t)pr.i01 * 384;
  const unsigned short* q10 = qb + (size_t)pr.i10 * 384;
  const unsigned short* q11 = qb + (size_t)pr.i11 * 384;
  unsigned short* oc = ccg + ((size_t)b * HWO + p) * CTOT + gp * 96 + half * 48;
  const float* gh = gsh + half * 48;
#pragma unroll
  for (int j = 0; j < 6; j++) {
    const uint4 v00 = *(const uint4*)(q00 + j * 8);
    const uint4 v01 = *(const uint4*)(q01 + j * 8);
    const uint4 v10 = *(const uint4*)(q10 + j * 8);
    const uint4 v11 = *(const uint4*)(q11 + j * 8);
    const unsigned short* s00 = (const unsigned short*)&v00;
    const unsigned short* s01 = (const unsigned short*)&v01;
    const unsigned short* s10 = (const unsigned short*)&v10;
    const unsigned short* s11 = (const unsigned short*)&v11;
    unsigned short r8[8];
#pragma unroll
    for (int jj = 0; jj < 8; jj++) {
      const float v = w00 * bf2f(s00[jj]) + w01 * bf2f(s01[jj]) +
                      w10 * bf2f(s10[jj]) + w11 * bf2f(s11[jj]);
      r8[jj] = f2bf(v * gh[j * 8 + jj]);
    }
    *(uint4*)(oc + j * 8) = *(const uint4*)r8;
  }
}

// ---------------------------------------------------------------------------
// Heads (position-major h).
// ---------------------------------------------------------------------------
__global__ __launch_bounds__(256) void head_pm(
    const unsigned short* __restrict__ h,
    const float* __restrict__ pred_w, const float* __restrict__ pred_b,
    const float* __restrict__ bird_w, const float* __restrict__ bird_b,
    float* __restrict__ out) {
  const int idx = blockIdx.x * 256 + threadIdx.x;
  const int b = idx >> 14, p = idx & 16383;
  const unsigned short* hb = h + ((size_t)b * HWO + p) * 384;
  float a0 = pred_b[0], a1 = pred_b[1], a2 = pred_b[2];
  float a3 = pred_b[3], a4 = pred_b[4], a5 = pred_b[5];
  float a6 = bird_b[0], a7 = bird_b[1];
  for (int c8 = 0; c8 < 384; c8 += 8) {
    const uint4 v = *(const uint4*)(hb + c8);
    const unsigned short* sv = (const unsigned short*)&v;
#pragma unroll
    for (int jj = 0; jj < 8; jj++) {
      const int o = c8 + jj;
      const float hv = bf2f(sv[jj]);
      const float* pw = pred_w + o * 6;
      a0 = fmaf(hv, pw[0], a0);
      a1 = fmaf(hv, pw[1], a1);
      a2 = fmaf(hv, pw[2], a2);
      a3 = fmaf(hv, pw[3], a3);
      a4 = fmaf(hv, pw[4], a4);
      a5 = fmaf(hv, pw[5], a5);
      a6 = fmaf(hv, bird_w[o * 2 + 0], a6);
      a7 = fmaf(hv, bird_w[o * 2 + 1], a7);
    }
  }
  float* ob = out + (size_t)b * 6 * HWO + p;
  ob[0] = a0; ob[HWO] = a1; ob[2 * HWO] = a2;
  ob[3 * HWO] = a3; ob[4 * HWO] = a4; ob[5 * HWO] = a5;
  float* ab = out + (size_t)12 * HWO + (size_t)b * 2 * HWO + p;
  ab[0] = a6; ab[HWO] = a7;
}

// ---------------------------------------------------------------------------
extern "C" void kernel_launch(void* const* d_in, const int* in_sizes, int n_in,
                              void* d_out, int out_size, void* d_ws, size_t ws_size,
                              hipStream_t stream) {
  const float* c1      = (const float*)d_in[0];
  const float* c2      = (const float*)d_in[1];
  const float* c3      = (const float*)d_in[2];
  const float* c4      = (const float*)d_in[3];
  const float* mlp1_w  = (const float*)d_in[4];
  const float* mlp1_b  = (const float*)d_in[5];
  const float* mlp2_w  = (const float*)d_in[6];
  const float* mlp2_b  = (const float*)d_in[7];
  const float* mlp3_w  = (const float*)d_in[8];
  const float* mlp3_b  = (const float*)d_in[9];
  const float* mlp4_w  = (const float*)d_in[10];
  const float* mlp4_b  = (const float*)d_in[11];
  const float* up2_w   = (const float*)d_in[12];
  const float* up2_b   = (const float*)d_in[13];
  const float* up4_w   = (const float*)d_in[14];
  const float* up4_b   = (const float*)d_in[15];
  const float* up8_w   = (const float*)d_in[16];
  const float* up8_b   = (const float*)d_in[17];
  const float* ssm_in_w    = (const float*)d_in[18];
  const float* ssm_in_b    = (const float*)d_in[19];
  const float* ssm_xproj_w = (const float*)d_in[20];
  const float* ssm_dt_w    = (const float*)d_in[21];
  const float* ssm_dt_b    = (const float*)d_in[22];
  const float* ssm_A_log   = (const float*)d_in[23];
  const float* ssm_D       = (const float*)d_in[24];
  const float* ssm_out_w   = (const float*)d_in[25];
  const float* ssm_out_b   = (const float*)d_in[26];
  const float* fuse_w  = (const float*)d_in[27];
  const float* bn_g    = (const float*)d_in[28];
  const float* bn_b    = (const float*)d_in[29];
  const float* bn_m    = (const float*)d_in[30];
  const float* bn_v    = (const float*)d_in[31];
  const float* pred_w  = (const float*)d_in[32];
  const float* pred_b  = (const float*)d_in[33];
  const float* bird_w  = (const float*)d_in[34];
  const float* bird_b  = (const float*)d_in[35];
  float* outp = (float*)d_out;
  (void)in_sizes; (void)n_in; (void)out_size; (void)ws_size;

  float* ws = (float*)d_ws;
  size_t off = 0;
  auto alloc = [&](size_t n) { float* p = ws + off; off += n; return p; };
  unsigned short* ccg = (unsigned short*)alloc(25165824);  // bf16 [2][16384][1536]
  unsigned short* bp4 = (unsigned short*)alloc(98304);     // bf16 [2][256][384]
  unsigned short* bp3 = (unsigned short*)alloc(393216);    // bf16 [2][1024][384]
  unsigned short* bp2 = (unsigned short*)alloc(1572864);   // bf16 [2][4096][384]
  float* bo4 = alloc(262144);                              // f32 [2][256][512]
  float* bo3 = alloc(262144);                              // f32 [2][1024][128]
  float* bo2 = alloc(262144);                              // f32 [2][4096][32]
  Prm* prm = (Prm*)alloc(1572864);                         // [2][12][16384]
  float* part = alloc(73728);                              // [32][2][1152]
  float* mc1  = alloc(192);
  float* ub   = alloc(196608);
  float2* dtdu = (float2*)alloc(393216);
  float* Bsb  = alloc(49152);
  float* Csb  = alloc(49152);
  float* yb   = alloc(393216);
  float* gteb = alloc(3072);
  float* scb  = alloc(384);
  float* shb  = alloc(384);
  unsigned short* hbf = (unsigned short*)alloc(6291456);   // bf16 [2][16384][384]
  unsigned short* t1  = (unsigned short*)(ws + off);
  unsigned short* t2  = t1 + 36864;
  unsigned short* t3  = t2 + 36864;
  unsigned short* t4  = t3 + 73728;
  unsigned short* t8  = t4 + 147456;
  unsigned short* t4u = t8 + 196608;
  unsigned short* t2u = t4u + 49152;
  unsigned short* wtf = t2u + 12288;    // bf16 [384][1536]

  // 0) setup: transposes + BN fold + mc1 + fuse_w transpose
  {
    SetupArgs sp;
    const float* Ws[7] = {mlp1_w, mlp2_w, mlp3_w, mlp4_w, up8_w, up4_w, up2_w};
    unsigned short* Ts[7] = {t1, t2, t3, t4, t8, t4u, t2u};
    const int Ks[7] = {96, 96, 192, 384, 384, 384, 384};
    const int Ns[7] = {384, 384, 384, 384, 512, 128, 32};
    int bs = 0;
    for (int i = 0; i < 7; i++) {
      sp.W[i] = Ws[i]; sp.T[i] = Ts[i]; sp.K[i] = Ks[i]; sp.N[i] = Ns[i];
      sp.bstart[i] = bs;
      bs += (Ks[i] * Ns[i] + 255) / 256;
    }
    sp.bstart[7] = bs;
    sp.nTP = bs;
    sp.bn_g = bn_g; sp.bn_v = bn_v; sp.bn_m = bn_m; sp.bn_b = bn_b;
    sp.sc = scb; sp.sh = shb;
    sp.c1 = c1; sp.mc1 = mc1;
    sp.fw = fuse_w; sp.fwt = wtf;
    hipLaunchKernelGGL(setup_kernel, dim3(bs + 2 + 192 + 576), dim3(256), 0, stream, sp);
  }

  // 1) small-map projections (c4, c3, c2)
  hipLaunchKernelGGL((pm_gemm<384, 2, 2, 4, 6, 0, 1>), dim3(2, 2, 2), dim3(256), 0, stream,
      (const void*)c4, t4, mlp4_b, nullptr, nullptr, (void*)bp4,
      256, (long)384 * 256, 0L, (long)256 * 384, 384, 0, 0);
  hipLaunchKernelGGL((pm_gemm<192, 2, 2, 4, 6, 0, 1>), dim3(8, 2, 2), dim3(256), 0, stream,
      (const void*)c3, t3, mlp3_b, nullptr, nullptr, (void*)bp3,
      1024, (long)192 * 1024, 0L, (long)1024 * 384, 384, 0, 0);
  hipLaunchKernelGGL((pm_gemm<96, 2, 2, 4, 6, 0, 1>), dim3(32, 2, 2), dim3(256), 0, stream,
      (const void*)c2, t2, mlp2_b, nullptr, nullptr, (void*)bp2,
      4096, (long)96 * 4096, 0L, (long)4096 * 384, 384, 0, 0);
  // 2) offset convs
  hipLaunchKernelGGL((pm_gemm<384, 2, 2, 4, 4, 1, 0>), dim3(2, 4, 2), dim3(256), 0, stream,
      (const void*)bp4, t8, up8_b, nullptr, nullptr, (void*)bo4,
      256, (long)256 * 384, 0L, (long)256 * 512, 512, 0, 0);
  hipLaunchKernelGGL((pm_gemm<384, 2, 2, 4, 4, 1, 0>), dim3(8, 1, 2), dim3(256), 0, stream,
      (const void*)bp3, t4u, up4_b, nullptr, nullptr, (void*)bo3,
      1024, (long)1024 * 384, 0L, (long)1024 * 128, 128, 0, 0);
  hipLaunchKernelGGL((pm_gemm<384, 4, 1, 2, 2, 1, 0>), dim3(32, 1, 2), dim3(256), 0, stream,
      (const void*)bp2, t2u, up2_b, nullptr, nullptr, (void*)bo2,
      4096, (long)4096 * 384, 0L, (long)4096 * 32, 32, 0, 0);
  // 3) bilinear params + per-channel mean partials
  hipLaunchKernelGGL(params_kernel, dim3(64, 12, 2), dim3(256), 0, stream,
                     bo4, bo3, bo2, prm);
  hipLaunchKernelGGL(mean_up, dim3(32, 12, 2), dim3(256), 0, stream,
                     bp4, bp3, bp2, prm, part);
  // 4) ssm prep + parallel scan + gate
  hipLaunchKernelGGL(ssm_prep, dim3(3072), dim3(64), 0, stream,
                     part, mc1, mlp1_w, mlp1_b, ssm_in_w, ssm_in_b,
                     ssm_xproj_w, ssm_dt_w, ssm_dt_b, ub, dtdu, Bsb, Csb);
  hipLaunchKernelGGL(ssm_scan_par, dim3(64, 2, 2), dim3(256), 0, stream,
                     dtdu, Bsb, Csb, ssm_A_log, yb);
  hipLaunchKernelGGL(gate_kernel, dim3(1536, 2), dim3(64), 0, stream,
                     yb, ub, ssm_D, ssm_out_w, ssm_out_b, gteb);
  // 5) c1 projection straight into gated cc (cols 1152..1536), gate in epilogue
  hipLaunchKernelGGL((pm_gemm<96, 2, 2, 4, 6, 0, 3>), dim3(128, 2, 2), dim3(256), 0, stream,
      (const void*)c1, t1, mlp1_b, gteb + 1152, nullptr, (void*)ccg,
      16384, (long)96 * 16384, 0L, (long)16384 * 1536, 1536, 1152, 1536);
  // 6) gated bilinear cc materialization (cols 0..1152)
  hipLaunchKernelGGL(cc_mat, dim3(128, 12, 2), dim3(256), 0, stream,
                     bp4, bp3, bp2, prm, gteb, ccg);
  // 7) fuse GEMM (batch-shared B) + BN + ReLU -> hbf
  hipLaunchKernelGGL((pm_gemm<1536, 2, 2, 4, 6, 1, 2>), dim3(128, 2, 2), dim3(256), 0, stream,
      (const void*)ccg, wtf, nullptr, scb, shb, (void*)hbf,
      16384, (long)16384 * 1536, 0L, (long)16384 * 384, 384, 0, 0);
  // 8) heads
  hipLaunchKernelGGL(head_pm, dim3(128), dim3(256), 0, stream,
                     hbf, pred_w, pred_b, bird_w, bird_b, outp);
}

// Round 9
// 294.772 us; speedup vs baseline: 1.2018x; 1.2018x over previous
//
#include <hip/hip_runtime.h>
#include <cstddef>

#define HWO 16384   // 128*128
#define CTOT 1536

typedef __attribute__((ext_vector_type(8))) short bf16x8;
typedef __attribute__((ext_vector_type(4))) float f32x4;

__device__ inline unsigned short f2bf(float x) {
  union { float f; unsigned u; } v; v.f = x;
  unsigned r = v.u + 0x7FFFu + ((v.u >> 16) & 1u);
  return (unsigned short)(r >> 16);
}
__device__ inline float bf2f(unsigned short h) {
  union { unsigned u; float f; } v; v.u = ((unsigned)h) << 16; return v.f;
}

struct __align__(16) Prm { unsigned short i00, i01, i10, i11; float wx, wy; };

// ---------------------------------------------------------------------------
// Setup: 7 weight transposes + BN fold + mc1 + fuse_w LDS-tiled transpose.
// ---------------------------------------------------------------------------
struct SetupArgs {
  const float* W[7];
  unsigned short* T[7];
  int K[7], N[7], bstart[8];
  const float *bn_g, *bn_v, *bn_m, *bn_b;
  float *sc, *sh;
  const float* c1;
  float* mc1;                 // [2*96]
  const float* fw;            // fuse_w [1536][384]
  unsigned short* fwt;        // [384][1536] bf16
  int nTP;
};
__global__ __launch_bounds__(256) void setup_kernel(SetupArgs a) {
  int bid = blockIdx.x;
  if (bid < a.nTP) {
    int s = 0;
#pragma unroll
    for (int i = 1; i < 7; i++) if (bid >= a.bstart[i]) s = i;
    const int K = a.K[s], N = a.N[s];
    const int idx = (bid - a.bstart[s]) * 256 + threadIdx.x;
    if (idx >= K * N) return;
    const int k = idx / N, o = idx - k * N;
    a.T[s][(size_t)o * K + k] = f2bf(a.W[s][idx]);
    return;
  }
  bid -= a.nTP;
  if (bid < 2) {   // BN fold
    const int o = bid * 256 + threadIdx.x;
    if (o < 384) {
      const float sc = a.bn_g[o] * rsqrtf(a.bn_v[o] + 1e-5f);
      a.sc[o] = sc;
      a.sh[o] = a.bn_b[o] - a.bn_m[o] * sc;
    }
    return;
  }
  bid -= 2;
  if (bid < 192) {  // mc1: one block per (b*96+ch)
    const float4* p = (const float4*)(a.c1 + (size_t)bid * HWO);
    float acc = 0.f;
    for (int i = threadIdx.x; i < HWO / 4; i += 256) {
      const float4 v = p[i];
      acc += (v.x + v.y) + (v.z + v.w);
    }
    for (int o = 32; o > 0; o >>= 1) acc += __shfl_down(acc, o, 64);
    __shared__ float red[4];
    if ((threadIdx.x & 63) == 0) red[threadIdx.x >> 6] = acc;
    __syncthreads();
    if (threadIdx.x == 0)
      a.mc1[bid] = (red[0] + red[1] + red[2] + red[3]) * (1.0f / HWO);
    return;
  }
  bid -= 192;       // fuse_w transpose: 48 k-tiles x 12 o-tiles (32x32)
  const int tk = bid / 12, to = bid % 12;
  __shared__ float tile[32][33];
  const int rr0 = threadIdx.x >> 5, cch = threadIdx.x & 31;
#pragma unroll
  for (int rr = rr0; rr < 32; rr += 8)
    tile[rr][cch] = a.fw[(size_t)(tk * 32 + rr) * 384 + to * 32 + cch];
  __syncthreads();
#pragma unroll
  for (int rr = rr0; rr < 32; rr += 8)
    a.fwt[(size_t)(to * 32 + rr) * 1536 + tk * 32 + cch] = f2bf(tile[cch][rr]);
}

// ---------------------------------------------------------------------------
// Position-major MFMA GEMM.
// XMODE 1: X bf16 [B][P][K]; XMODE 0: X f32 [B][K][P] (transpose in staging).
// OMODE 0: f32 +bias | 1: bf16 +bias.
// ---------------------------------------------------------------------------
template<int K, int WM, int WN, int MT, int OT, int XMODE, int OMODE>
__global__ __launch_bounds__(WM * WN * 64) void pm_gemm(
    const void* __restrict__ Xv, const unsigned short* __restrict__ Wt,
    const float* __restrict__ bias, void* __restrict__ Yv,
    int P, long x_bs, long y_bs, int yrs, int ycol) {
  constexpr int BM = WM * MT * 16, BN = WN * OT * 16, NTH = WM * WN * 64;
  constexpr int BK = (K % 64 == 0) ? 64 : 32;
  constexpr int LST = BK + 8;
  static_assert(XMODE == 1 || BM == 128, "XMODE0 staging assumes BM=128");
  __shared__ unsigned short Alds[BM * LST];
  __shared__ unsigned short Blds[BN * LST];
  const int tid = threadIdx.x;
  const int w = tid >> 6, lane = tid & 63;
  const int wm = w / WN, wn = w % WN;
  const int b = blockIdx.z;
  const int p0 = blockIdx.x * BM;
  const int o0 = blockIdx.y * BN;
  const unsigned short* Wb = Wt + (long)o0 * K;
  f32x4 acc[MT * OT];
#pragma unroll
  for (int i = 0; i < MT * OT; i++) acc[i] = (f32x4){0.f, 0.f, 0.f, 0.f};
  const int lr = lane & 15, lk = (lane >> 4) * 8;

  for (int kc = 0; kc < K; kc += BK) {
    if constexpr (XMODE == 1) {
      const unsigned short* Xb = (const unsigned short*)Xv + (long)b * x_bs;
#pragma unroll
      for (int it = 0; it < BM * (BK / 8) / NTH; it++) {
        const int idx = tid + it * NTH;
        const int r = idx / (BK / 8), ck = (idx % (BK / 8)) * 8;
        *(uint4*)&Alds[r * LST + ck] =
            *(const uint4*)(Xb + (long)(p0 + r) * K + kc + ck);
      }
    } else {
      const float* Xf = (const float*)Xv + (long)b * x_bs;
#pragma unroll
      for (int it = 0; it < BK * 32 / NTH; it++) {
        const int idx = tid + it * NTH;
        const int k = idx >> 5, pg = (idx & 31) * 4;
        const float4 v = *(const float4*)(Xf + (long)(kc + k) * P + p0 + pg);
        Alds[(pg + 0) * LST + k] = f2bf(v.x);
        Alds[(pg + 1) * LST + k] = f2bf(v.y);
        Alds[(pg + 2) * LST + k] = f2bf(v.z);
        Alds[(pg + 3) * LST + k] = f2bf(v.w);
      }
    }
#pragma unroll
    for (int it = 0; it < BN * (BK / 8) / NTH; it++) {
      const int idx = tid + it * NTH;
      const int r = idx / (BK / 8), ck = (idx % (BK / 8)) * 8;
      *(uint4*)&Blds[r * LST + ck] =
          *(const uint4*)(Wb + (long)r * K + kc + ck);
    }
    __syncthreads();
#pragma unroll
    for (int kk = 0; kk < BK; kk += 32) {
      bf16x8 af[MT];
#pragma unroll
      for (int mt = 0; mt < MT; mt++)
        af[mt] = *(const bf16x8*)&Alds[((wm * MT + mt) * 16 + lr) * LST + kk + lk];
#pragma unroll
      for (int ot = 0; ot < OT; ot++) {
        const bf16x8 bfr =
            *(const bf16x8*)&Blds[((wn * OT + ot) * 16 + lr) * LST + kk + lk];
#pragma unroll
        for (int mt = 0; mt < MT; mt++)
          acc[mt * OT + ot] = __builtin_amdgcn_mfma_f32_16x16x32_bf16(
              af[mt], bfr, acc[mt * OT + ot], 0, 0, 0);
      }
    }
    __syncthreads();
  }
  const int r0 = (lane >> 4) * 4;
#pragma unroll
  for (int mt = 0; mt < MT; mt++) {
#pragma unroll
    for (int ot = 0; ot < OT; ot++) {
      const int o = o0 + (wn * OT + ot) * 16 + lr;
      const f32x4 r = acc[mt * OT + ot];
      const float bv = bias ? bias[o] : 0.f;
#pragma unroll
      for (int jj = 0; jj < 4; jj++) {
        const long row = p0 + (wm * MT + mt) * 16 + r0 + jj;
        const float v = r[jj] + bv;
        if constexpr (OMODE == 0)
          ((float*)Yv)[(long)b * y_bs + row * yrs + ycol + o] = v;
        else
          ((unsigned short*)Yv)[(long)b * y_bs + row * yrs + ycol + o] = f2bf(v);
      }
    }
  }
}

// ---------------------------------------------------------------------------
// Bilinear sampling params per (b, g'=lvl*4+g, output pixel).
// ---------------------------------------------------------------------------
__global__ __launch_bounds__(256) void params_kernel(
    const float* __restrict__ bo4, const float* __restrict__ bo3,
    const float* __restrict__ bo2, Prm* __restrict__ prm) {
  const int gp = blockIdx.y, b = blockIdx.z;
  const int p = blockIdx.x * 256 + threadIdx.x;
  const int lvl = gp >> 2, g = gp & 3;
  const float* bo; int ls, H, offC;
  if (lvl == 0)      { bo = bo4; ls = 3; H = 16; offC = 512; }
  else if (lvl == 1) { bo = bo3; ls = 2; H = 32; offC = 128; }
  else               { bo = bo2; ls = 1; H = 64; offC = 32; }
  const int s = 1 << ls, ss = s * s, W = H, HWs = H * H;
  const int yo = p >> 7, xo = p & 127;
  const int h = yo >> ls, i = yo & (s - 1);
  const int w = xo >> ls, j = xo & (s - 1);
  const int sp = h * W + w;
  const float* offp = bo + ((size_t)b * HWs + sp) * offC;
  const float cx = offp[g * ss + i * s + j];
  const float cy = offp[(4 + g) * ss + i * s + j];
  const float inv_s = 1.0f / (float)s;
  const float offx = cx * 0.25f + ((float)j - (s - 1) * 0.5f) * inv_s;
  const float offy = cy * 0.25f + ((float)i - (s - 1) * 0.5f) * inv_s;
  float xf = fminf(fmaxf((float)w + offx, 0.0f), (float)(W - 1));
  float yf = fminf(fmaxf((float)h + offy, 0.0f), (float)(H - 1));
  const float x0f = floorf(xf), y0f = floorf(yf);
  const int x0 = (int)x0f, y0 = (int)y0f;
  const int x1 = min(x0 + 1, W - 1), y1 = min(y0 + 1, H - 1);
  Prm pr;
  pr.i00 = (unsigned short)(y0 * W + x0);
  pr.i01 = (unsigned short)(y0 * W + x1);
  pr.i10 = (unsigned short)(y1 * W + x0);
  pr.i11 = (unsigned short)(y1 * W + x1);
  pr.wx = xf - x0f;
  pr.wy = yf - y0f;
  prm[((size_t)b * 12 + gp) * HWO + p] = pr;
}

// ---------------------------------------------------------------------------
// Per-channel sums of the virtual upsampled maps -> partials.
// ---------------------------------------------------------------------------
__global__ __launch_bounds__(256) void mean_up(
    const unsigned short* __restrict__ bp4, const unsigned short* __restrict__ bp3,
    const unsigned short* __restrict__ bp2, const Prm* __restrict__ prm,
    float* __restrict__ part) {
  const int gp = blockIdx.y, b = blockIdx.z;
  const int lvl = gp >> 2, g = gp & 3;
  const unsigned short* bpL; int HWs_;
  if (lvl == 0)      { bpL = bp4; HWs_ = 256; }
  else if (lvl == 1) { bpL = bp3; HWs_ = 1024; }
  else               { bpL = bp2; HWs_ = 4096; }
  const int tid = threadIdx.x;
  const int chunk = tid % 12, pl = tid / 12;
  float acc[8];
#pragma unroll
  for (int j = 0; j < 8; j++) acc[j] = 0.f;
  const Prm* pp = prm + ((size_t)b * 12 + gp) * HWO + blockIdx.x * 512;
  const unsigned short* qb = bpL + (size_t)b * HWs_ * 384 + g * 96 + chunk * 8;
  if (tid < 252) {
    for (int it = 0; it < 25; it++) {
      const int pli = it * 21 + pl;
      if (pli < 512) {
        const Prm pr = pp[pli];
        const float wx = pr.wx, wy = pr.wy;
        const float w00 = (1.f - wx) * (1.f - wy), w01 = wx * (1.f - wy);
        const float w10 = (1.f - wx) * wy, w11 = wx * wy;
        const uint4 v00 = *(const uint4*)(qb + (size_t)pr.i00 * 384);
        const uint4 v01 = *(const uint4*)(qb + (size_t)pr.i01 * 384);
        const uint4 v10 = *(const uint4*)(qb + (size_t)pr.i10 * 384);
        const uint4 v11 = *(const uint4*)(qb + (size_t)pr.i11 * 384);
        const unsigned short* s00 = (const unsigned short*)&v00;
        const unsigned short* s01 = (const unsigned short*)&v01;
        const unsigned short* s10 = (const unsigned short*)&v10;
        const unsigned short* s11 = (const unsigned short*)&v11;
#pragma unroll
        for (int j = 0; j < 8; j++)
          acc[j] += w00 * bf2f(s00[j]) + w01 * bf2f(s01[j]) +
                    w10 * bf2f(s10[j]) + w11 * bf2f(s11[j]);
      }
    }
  }
  __shared__ float red[12][8][22];
  if (tid < 252) {
#pragma unroll
    for (int j = 0; j < 8; j++) red[chunk][j][pl] = acc[j];
  }
  __syncthreads();
  if (tid < 96) {
    float s = 0.f;
#pragma unroll
    for (int l = 0; l < 21; l++) s += red[tid >> 3][tid & 7][l];
    part[((size_t)blockIdx.x * 2 + b) * 1152 + gp * 96 + tid] = s;
  }
}

// ---------------------------------------------------------------------------
// SSM prep (mean from partials or mc1 path).
// ---------------------------------------------------------------------------
__global__ __launch_bounds__(64) void ssm_prep(
    const float* __restrict__ part, const float* __restrict__ mc1,
    const float* __restrict__ mlp1_w, const float* __restrict__ mlp1_b,
    const float* __restrict__ in_w, const float* __restrict__ in_b,
    const float* __restrict__ xproj_w, const float* __restrict__ dt_w,
    const float* __restrict__ dt_b, float* __restrict__ u_out,
    float2* __restrict__ dtdu_out, float* __restrict__ Bs_out,
    float* __restrict__ Cs_out) {
  const int bc = blockIdx.x;
  const int b = bc / 1536, c = bc - b * 1536;
  const int d = threadIdx.x;
  float sv;
  if (c < 1152) {
    float a = (d < 32) ? part[((size_t)d * 2 + b) * 1152 + c] : 0.f;
    a += __shfl_xor(a, 1, 64);  a += __shfl_xor(a, 2, 64);
    a += __shfl_xor(a, 4, 64);  a += __shfl_xor(a, 8, 64);
    a += __shfl_xor(a, 16, 64); a += __shfl_xor(a, 32, 64);
    sv = a * (1.0f / HWO);
  } else {
    const int c2 = c - 1152;
    float a = mc1[b * 96 + d] * mlp1_w[d * 384 + c2];
    if (d < 32) a += mc1[b * 96 + 64 + d] * mlp1_w[(64 + d) * 384 + c2];
    a += __shfl_xor(a, 1, 64);  a += __shfl_xor(a, 2, 64);
    a += __shfl_xor(a, 4, 64);  a += __shfl_xor(a, 8, 64);
    a += __shfl_xor(a, 16, 64); a += __shfl_xor(a, 32, 64);
    sv = a + mlp1_b[c2];
  }
  const float u = sv * in_w[d] + in_b[d];
  __shared__ float ush[64];
  __shared__ float proj[33];
  ush[d] = u;
  __syncthreads();
  if (d < 33) {
    float acc = 0.f;
    for (int k = 0; k < 64; k++) acc = fmaf(ush[k], xproj_w[k * 33 + d], acc);
    proj[d] = acc;
  }
  __syncthreads();
  float dtv = proj[0] * dt_w[d] + dt_b[d];
  dtv = (dtv > 20.0f) ? dtv : log1pf(__expf(dtv));   // softplus
  u_out[(size_t)bc * 64 + d] = u;
  dtdu_out[(size_t)bc * 64 + d] = make_float2(dtv, dtv * u);
  if (d < 16) {
    Bs_out[(size_t)bc * 16 + d] = proj[1 + d];
    Cs_out[(size_t)bc * 16 + d] = proj[17 + d];
  }
}

// ---------------------------------------------------------------------------
// Parallel associative scan. grid = (64 d, 2 dir, 2 b), block 256.
// ---------------------------------------------------------------------------
__global__ __launch_bounds__(256) void ssm_scan_par(
    const float2* __restrict__ dtdu, const float* __restrict__ Bs,
    const float* __restrict__ Cs, const float* __restrict__ A_log,
    float* __restrict__ y) {
  const int d = blockIdx.x, dir = blockIdx.y, b = blockIdx.z;
  const int t = threadIdx.x;
  const int j = t >> 4, n = t & 15;
  const float A = -__expf(A_log[d * 16 + n]);
  const int s0 = j * 96;
  const int c0 = dir ? (1535 - s0) : s0;
  const int step = dir ? -1 : 1;
  const float2* dbase = dtdu + (size_t)b * 1536 * 64 + (size_t)c0 * 64 + d;
  const float* bbase = Bs + (size_t)b * 1536 * 16 + (size_t)c0 * 16 + n;
  const float* cbase = Cs + (size_t)b * 1536 * 16 + (size_t)c0 * 16 + n;
  const long dstep = (long)step * 64;
  const long bstep = (long)step * 16;

  float Ap = 1.f, Bp = 0.f;
  {
    const float2* dp = dbase;
    const float* bp = bbase;
    float2 td = *dp;
    float Bv = *bp;
    for (int i = 0; i < 96; i++) {
      const float2 tdc = td;
      const float Bc = Bv;
      dp += dstep; bp += bstep;
      if (i + 1 < 96) { td = *dp; Bv = *bp; }
      const float a = __expf(tdc.x * A);
      Bp = fmaf(a, Bp, tdc.y * Bc);
      Ap *= a;
    }
  }
  __shared__ float sA[16][16], sB[16][16];
  sA[j][n] = Ap;
  sB[j][n] = Bp;
  __syncthreads();
  float H = 0.f;
  for (int jj = 0; jj < j; jj++) H = fmaf(sA[jj][n], H, sB[jj][n]);

  float* yb = y + (size_t)(b * 2 + dir) * 1536 * 64;
  {
    const float2* dp = dbase;
    const float* bp = bbase;
    const float* cp = cbase;
    float2 td = *dp;
    float Bv = *bp;
    float Cv = *cp;
    float h = H;
    int c = c0;
    for (int i = 0; i < 96; i++) {
      const float2 tdc = td;
      const float Bc = Bv, Cc = Cv;
      dp += dstep; bp += bstep; cp += bstep;
      if (i + 1 < 96) { td = *dp; Bv = *bp; Cv = *cp; }
      const float a = __expf(tdc.x * A);
      h = fmaf(a, h, tdc.y * Bc);
      float pr = h * Cc;
      pr += __shfl_xor(pr, 1, 64);
      pr += __shfl_xor(pr, 2, 64);
      pr += __shfl_xor(pr, 4, 64);
      pr += __shfl_xor(pr, 8, 64);
      if (n == 0) yb[(size_t)c * 64 + d] = pr;
      c += step;
    }
  }
}

// ---------------------------------------------------------------------------
// Gate.
// ---------------------------------------------------------------------------
__global__ __launch_bounds__(64) void gate_kernel(
    const float* __restrict__ y, const float* __restrict__ u,
    const float* __restrict__ Dp, const float* __restrict__ out_w,
    const float* __restrict__ out_b, float* __restrict__ gate) {
  const int c = blockIdx.x, b = blockIdx.y, d = threadIdx.x;
  const size_t i = ((size_t)b * 1536 + c) * 64 + d;
  float yt = y[((size_t)(b * 2) * 1536 + c) * 64 + d]
           + y[((size_t)(b * 2 + 1) * 1536 + c) * 64 + d]
           + Dp[d] * u[i];
  float v = yt * out_w[d];
  for (int o = 32; o > 0; o >>= 1) v += __shfl_down(v, o, 64);
  if (d == 0) gate[b * 1536 + c] = 1.0f / (1.0f + __expf(-(v + out_b[0])));
}

// ---------------------------------------------------------------------------
// wg[b][o][k] = wtf[o][k] * gate[b][k]  (coalesced, bf16; real div for k0).
// ---------------------------------------------------------------------------
__global__ __launch_bounds__(256) void gate_fold(
    const unsigned short* __restrict__ wtf, const float* __restrict__ gate,
    unsigned short* __restrict__ wg) {
  const int b = blockIdx.y;
  const int idx8 = blockIdx.x * 256 + threadIdx.x;   // 0..73727 (16B groups)
  const int o = idx8 / 192;                          // 192 groups of 8 per row
  const int k0 = (idx8 - o * 192) * 8;
  const size_t idx = (size_t)o * 1536 + k0;
  const uint4 v = *(const uint4*)(wtf + idx);
  const unsigned short* s = (const unsigned short*)&v;
  const float* g = gate + b * 1536 + k0;
  unsigned short r8[8];
#pragma unroll
  for (int j = 0; j < 8; j++) r8[j] = f2bf(bf2f(s[j]) * g[j]);
  *(uint4*)(wg + (size_t)b * 589824 + idx) = *(const uint4*)r8;
}

// ---------------------------------------------------------------------------
// Fuse GEMM, single o-pass (BN=384): A gathered on the fly from bp maps
// (k<1152, bilinear blend) or copied from bp1 (k>=1152). 512 thr, 8 waves.
// BM=64, BK=64. grid (256, 2). LDS 63 KB -> 2 blocks/CU.
// ---------------------------------------------------------------------------
__global__ __launch_bounds__(512) void fuse_gemm(
    const unsigned short* __restrict__ bp4, const unsigned short* __restrict__ bp3,
    const unsigned short* __restrict__ bp2, const unsigned short* __restrict__ bp1,
    const Prm* __restrict__ prm, const unsigned short* __restrict__ wg,
    const float* __restrict__ ep_a, const float* __restrict__ ep_b,
    unsigned short* __restrict__ hbf) {
  constexpr int LST = 72;
  __shared__ unsigned short Alds[64 * LST];    // 9216 B
  __shared__ unsigned short Blds[384 * LST];   // 55296 B
  const int tid = threadIdx.x;
  const int w = tid >> 6, lane = tid & 63;
  const int wm = w >> 2, wn = w & 3;           // 2 x 4 waves
  const int b = blockIdx.y;
  const int p0 = blockIdx.x * 64;
  const unsigned short* Wb = wg + (size_t)b * 589824;
  f32x4 acc[12];
#pragma unroll
  for (int i = 0; i < 12; i++) acc[i] = (f32x4){0.f, 0.f, 0.f, 0.f};
  const int lr = lane & 15, lk = (lane >> 4) * 8;
  const int ar = tid >> 3, ag = tid & 7;       // A-staging row / 8-col group

  for (int kc = 0; kc < 1536; kc += 64) {
    // ---- stage A: 64 rows x 64 k (one 16B group per thread)
    if (kc < 1152) {
      const int k8 = kc + ag * 8;
      const int gp = k8 / 96;                  // 0..11
      const int colL = k8 - (gp >> 2) * 384;   // col within level panel
      const int lvl = gp >> 2;
      const unsigned short* bpL; int HWs_;
      if (lvl == 0)      { bpL = bp4; HWs_ = 256; }
      else if (lvl == 1) { bpL = bp3; HWs_ = 1024; }
      else               { bpL = bp2; HWs_ = 4096; }
      const Prm pr = prm[((size_t)b * 12 + gp) * HWO + p0 + ar];
      const float wx = pr.wx, wy = pr.wy;
      const float w00 = (1.f - wx) * (1.f - wy), w01 = wx * (1.f - wy);
      const float w10 = (1.f - wx) * wy, w11 = wx * wy;
      const unsigned short* qb = bpL + (size_t)b * HWs_ * 384 + colL;
      const uint4 v00 = *(const uint4*)(qb + (size_t)pr.i00 * 384);
      const uint4 v01 = *(const uint4*)(qb + (size_t)pr.i01 * 384);
      const uint4 v10 = *(const uint4*)(qb + (size_t)pr.i10 * 384);
      const uint4 v11 = *(const uint4*)(qb + (size_t)pr.i11 * 384);
      const unsigned short* s00 = (const unsigned short*)&v00;
      const unsigned short* s01 = (const unsigned short*)&v01;
      const unsigned short* s10 = (const unsigned short*)&v10;
      const unsigned short* s11 = (const unsigned short*)&v11;
      unsigned short r8[8];
#pragma unroll
      for (int jj = 0; jj < 8; jj++)
        r8[jj] = f2bf(w00 * bf2f(s00[jj]) + w01 * bf2f(s01[jj]) +
                      w10 * bf2f(s10[jj]) + w11 * bf2f(s11[jj]));
      *(uint4*)&Alds[ar * LST + ag * 8] = *(const uint4*)r8;
    } else {
      *(uint4*)&Alds[ar * LST + ag * 8] =
          *(const uint4*)(bp1 + ((size_t)b * HWO + p0 + ar) * 384 +
                          (kc - 1152) + ag * 8);
    }
    // ---- stage B: 384 rows x 64 k
#pragma unroll
    for (int it = 0; it < 6; it++) {
      const int idx = tid + it * 512;
      const int r = idx >> 3, ck = (idx & 7) * 8;
      *(uint4*)&Blds[r * LST + ck] =
          *(const uint4*)(Wb + (size_t)r * 1536 + kc + ck);
    }
    __syncthreads();
#pragma unroll
    for (int kk = 0; kk < 64; kk += 32) {
      bf16x8 af[2];
#pragma unroll
      for (int mt = 0; mt < 2; mt++)
        af[mt] = *(const bf16x8*)&Alds[((wm * 2 + mt) * 16 + lr) * LST + kk + lk];
#pragma unroll
      for (int ot = 0; ot < 6; ot++) {
        const bf16x8 bfr =
            *(const bf16x8*)&Blds[((wn * 6 + ot) * 16 + lr) * LST + kk + lk];
#pragma unroll
        for (int mt = 0; mt < 2; mt++)
          acc[mt * 6 + ot] = __builtin_amdgcn_mfma_f32_16x16x32_bf16(
              af[mt], bfr, acc[mt * 6 + ot], 0, 0, 0);
      }
    }
    __syncthreads();
  }
  const int r0 = (lane >> 4) * 4;
#pragma unroll
  for (int mt = 0; mt < 2; mt++) {
#pragma unroll
    for (int ot = 0; ot < 6; ot++) {
      const int o = (wn * 6 + ot) * 16 + lr;
      const float sa = ep_a[o], sb = ep_b[o];
      const f32x4 r = acc[mt * 6 + ot];
#pragma unroll
      for (int jj = 0; jj < 4; jj++) {
        const size_t row = p0 + (wm * 2 + mt) * 16 + r0 + jj;
        hbf[((size_t)b * HWO + row) * 384 + o] =
            f2bf(fmaxf(fmaf(r[jj], sa, sb), 0.f));
      }
    }
  }
}

// ---------------------------------------------------------------------------
// Heads (position-major h).
// ---------------------------------------------------------------------------
__global__ __launch_bounds__(256) void head_pm(
    const unsigned short* __restrict__ h,
    const float* __restrict__ pred_w, const float* __restrict__ pred_b,
    const float* __restrict__ bird_w, const float* __restrict__ bird_b,
    float* __restrict__ out) {
  const int idx = blockIdx.x * 256 + threadIdx.x;
  const int b = idx >> 14, p = idx & 16383;
  const unsigned short* hb = h + ((size_t)b * HWO + p) * 384;
  float a0 = pred_b[0], a1 = pred_b[1], a2 = pred_b[2];
  float a3 = pred_b[3], a4 = pred_b[4], a5 = pred_b[5];
  float a6 = bird_b[0], a7 = bird_b[1];
  for (int c8 = 0; c8 < 384; c8 += 8) {
    const uint4 v = *(const uint4*)(hb + c8);
    const unsigned short* sv = (const unsigned short*)&v;
#pragma unroll
    for (int jj = 0; jj < 8; jj++) {
      const int o = c8 + jj;
      const float hv = bf2f(sv[jj]);
      const float* pw = pred_w + o * 6;
      a0 = fmaf(hv, pw[0], a0);
      a1 = fmaf(hv, pw[1], a1);
      a2 = fmaf(hv, pw[2], a2);
      a3 = fmaf(hv, pw[3], a3);
      a4 = fmaf(hv, pw[4], a4);
      a5 = fmaf(hv, pw[5], a5);
      a6 = fmaf(hv, bird_w[o * 2 + 0], a6);
      a7 = fmaf(hv, bird_w[o * 2 + 1], a7);
    }
  }
  float* ob = out + (size_t)b * 6 * HWO + p;
  ob[0] = a0; ob[HWO] = a1; ob[2 * HWO] = a2;
  ob[3 * HWO] = a3; ob[4 * HWO] = a4; ob[5 * HWO] = a5;
  float* ab = out + (size_t)12 * HWO + (size_t)b * 2 * HWO + p;
  ab[0] = a6; ab[HWO] = a7;
}

// ---------------------------------------------------------------------------
extern "C" void kernel_launch(void* const* d_in, const int* in_sizes, int n_in,
                              void* d_out, int out_size, void* d_ws, size_t ws_size,
                              hipStream_t stream) {
  const float* c1      = (const float*)d_in[0];
  const float* c2      = (const float*)d_in[1];
  const float* c3      = (const float*)d_in[2];
  const float* c4      = (const float*)d_in[3];
  const float* mlp1_w  = (const float*)d_in[4];
  const float* mlp1_b  = (const float*)d_in[5];
  const float* mlp2_w  = (const float*)d_in[6];
  const float* mlp2_b  = (const float*)d_in[7];
  const float* mlp3_w  = (const float*)d_in[8];
  const float* mlp3_b  = (const float*)d_in[9];
  const float* mlp4_w  = (const float*)d_in[10];
  const float* mlp4_b  = (const float*)d_in[11];
  const float* up2_w   = (const float*)d_in[12];
  const float* up2_b   = (const float*)d_in[13];
  const float* up4_w   = (const float*)d_in[14];
  const float* up4_b   = (const float*)d_in[15];
  const float* up8_w   = (const float*)d_in[16];
  const float* up8_b   = (const float*)d_in[17];
  const float* ssm_in_w    = (const float*)d_in[18];
  const float* ssm_in_b    = (const float*)d_in[19];
  const float* ssm_xproj_w = (const float*)d_in[20];
  const float* ssm_dt_w    = (const float*)d_in[21];
  const float* ssm_dt_b    = (const float*)d_in[22];
  const float* ssm_A_log   = (const float*)d_in[23];
  const float* ssm_D       = (const float*)d_in[24];
  const float* ssm_out_w   = (const float*)d_in[25];
  const float* ssm_out_b   = (const float*)d_in[26];
  const float* fuse_w  = (const float*)d_in[27];
  const float* bn_g    = (const float*)d_in[28];
  const float* bn_b    = (const float*)d_in[29];
  const float* bn_m    = (const float*)d_in[30];
  const float* bn_v    = (const float*)d_in[31];
  const float* pred_w  = (const float*)d_in[32];
  const float* pred_b  = (const float*)d_in[33];
  const float* bird_w  = (const float*)d_in[34];
  const float* bird_b  = (const float*)d_in[35];
  float* outp = (float*)d_out;
  (void)in_sizes; (void)n_in; (void)out_size; (void)ws_size;

  float* ws = (float*)d_ws;
  size_t off = 0;
  auto alloc = [&](size_t n) { float* p = ws + off; off += n; return p; };
  // NOTE: alloc() counts FLOATS. bf16 [2][16384][384] = 12.58M ushorts
  // = 6291456 floats (round-7/8 had these halved -> buffer overlap bug).
  unsigned short* bp1 = (unsigned short*)alloc(6291456);   // bf16 [2][16384][384]
  unsigned short* bp4 = (unsigned short*)alloc(98304);     // bf16 [2][256][384]
  unsigned short* bp3 = (unsigned short*)alloc(393216);    // bf16 [2][1024][384]
  unsigned short* bp2 = (unsigned short*)alloc(1572864);   // bf16 [2][4096][384]
  float* bo4 = alloc(262144);                              // f32 [2][256][512]
  float* bo3 = alloc(262144);                              // f32 [2][1024][128]
  float* bo2 = alloc(262144);                              // f32 [2][4096][32]
  Prm* prm = (Prm*)alloc(1572864);                         // [2][12][16384] x16B
  float* part = alloc(73728);                              // [32][2][1152]
  float* mc1  = alloc(192);
  float* ub   = alloc(196608);
  float2* dtdu = (float2*)alloc(393216);
  float* Bsb  = alloc(49152);
  float* Csb  = alloc(49152);
  float* yb   = alloc(393216);
  float* gteb = alloc(3072);
  float* scb  = alloc(384);
  float* shb  = alloc(384);
  unsigned short* hbf = (unsigned short*)alloc(6291456);   // bf16 [2][16384][384]
  unsigned short* t1  = (unsigned short*)(ws + off);
  unsigned short* t2  = t1 + 36864;
  unsigned short* t3  = t2 + 36864;
  unsigned short* t4  = t3 + 73728;
  unsigned short* t8  = t4 + 147456;
  unsigned short* t4u = t8 + 196608;
  unsigned short* t2u = t4u + 49152;
  unsigned short* wtf = t2u + 12288;        // bf16 [384][1536]
  unsigned short* wg  = wtf + 589824;       // bf16 [2][384][1536]

  // 0) setup: transposes + BN fold + mc1 + fuse_w transpose
  {
    SetupArgs sp;
    const float* Ws[7] = {mlp1_w, mlp2_w, mlp3_w, mlp4_w, up8_w, up4_w, up2_w};
    unsigned short* Ts[7] = {t1, t2, t3, t4, t8, t4u, t2u};
    const int Ks[7] = {96, 96, 192, 384, 384, 384, 384};
    const int Ns[7] = {384, 384, 384, 384, 512, 128, 32};
    int bs = 0;
    for (int i = 0; i < 7; i++) {
      sp.W[i] = Ws[i]; sp.T[i] = Ts[i]; sp.K[i] = Ks[i]; sp.N[i] = Ns[i];
      sp.bstart[i] = bs;
      bs += (Ks[i] * Ns[i] + 255) / 256;
    }
    sp.bstart[7] = bs;
    sp.nTP = bs;
    sp.bn_g = bn_g; sp.bn_v = bn_v; sp.bn_m = bn_m; sp.bn_b = bn_b;
    sp.sc = scb; sp.sh = shb;
    sp.c1 = c1; sp.mc1 = mc1;
    sp.fw = fuse_w; sp.fwt = wtf;
    hipLaunchKernelGGL(setup_kernel, dim3(bs + 2 + 192 + 576), dim3(256), 0, stream, sp);
  }

  // 1) projections (position-major bf16)
  hipLaunchKernelGGL((pm_gemm<384, 2, 2, 4, 6, 0, 1>), dim3(2, 2, 2), dim3(256), 0, stream,
      (const void*)c4, t4, mlp4_b, (void*)bp4, 256, (long)384 * 256, (long)256 * 384, 384, 0);
  hipLaunchKernelGGL((pm_gemm<192, 2, 2, 4, 6, 0, 1>), dim3(8, 2, 2), dim3(256), 0, stream,
      (const void*)c3, t3, mlp3_b, (void*)bp3, 1024, (long)192 * 1024, (long)1024 * 384, 384, 0);
  hipLaunchKernelGGL((pm_gemm<96, 2, 2, 4, 6, 0, 1>), dim3(32, 2, 2), dim3(256), 0, stream,
      (const void*)c2, t2, mlp2_b, (void*)bp2, 4096, (long)96 * 4096, (long)4096 * 384, 384, 0);
  hipLaunchKernelGGL((pm_gemm<96, 2, 2, 4, 6, 0, 1>), dim3(128, 2, 2), dim3(256), 0, stream,
      (const void*)c1, t1, mlp1_b, (void*)bp1, 16384, (long)96 * 16384, (long)16384 * 384, 384, 0);
  // 2) offset convs
  hipLaunchKernelGGL((pm_gemm<384, 2, 2, 4, 4, 1, 0>), dim3(2, 4, 2), dim3(256), 0, stream,
      (const void*)bp4, t8, up8_b, (void*)bo4, 256, (long)256 * 384, (long)256 * 512, 512, 0);
  hipLaunchKernelGGL((pm_gemm<384, 2, 2, 4, 4, 1, 0>), dim3(8, 1, 2), dim3(256), 0, stream,
      (const void*)bp3, t4u, up4_b, (void*)bo3, 1024, (long)1024 * 384, (long)1024 * 128, 128, 0);
  hipLaunchKernelGGL((pm_gemm<384, 4, 1, 2, 2, 1, 0>), dim3(32, 1, 2), dim3(256), 0, stream,
      (const void*)bp2, t2u, up2_b, (void*)bo2, 4096, (long)4096 * 384, (long)4096 * 32, 32, 0);
  // 3) bilinear params + per-channel mean partials
  hipLaunchKernelGGL(params_kernel, dim3(64, 12, 2), dim3(256), 0, stream,
                     bo4, bo3, bo2, prm);
  hipLaunchKernelGGL(mean_up, dim3(32, 12, 2), dim3(256), 0, stream,
                     bp4, bp3, bp2, prm, part);
  // 4) ssm prep + parallel scan + gate
  hipLaunchKernelGGL(ssm_prep, dim3(3072), dim3(64), 0, stream,
                     part, mc1, mlp1_w, mlp1_b, ssm_in_w, ssm_in_b,
                     ssm_xproj_w, ssm_dt_w, ssm_dt_b, ub, dtdu, Bsb, Csb);
  hipLaunchKernelGGL(ssm_scan_par, dim3(64, 2, 2), dim3(256), 0, stream,
                     dtdu, Bsb, Csb, ssm_A_log, yb);
  hipLaunchKernelGGL(gate_kernel, dim3(1536, 2), dim3(64), 0, stream,
                     yb, ub, ssm_D, ssm_out_w, ssm_out_b, gteb);
  // 5) per-batch gated weights (coalesced)
  hipLaunchKernelGGL(gate_fold, dim3(288, 2), dim3(256), 0, stream, wtf, gteb, wg);
  // 6) fused gather-GEMM + BN + ReLU -> hbf (cc never materialized)
  hipLaunchKernelGGL(fuse_gemm, dim3(256, 2), dim3(512), 0, stream,
                     bp4, bp3, bp2, bp1, prm, wg, scb, shb, hbf);
  // 7) heads
  hipLaunchKernelGGL(head_pm, dim3(128), dim3(256), 0, stream,
                     hbf, pred_w, pred_b, bird_w, bird_b, outp);
}

// Round 10
// 223.787 us; speedup vs baseline: 1.5831x; 1.3172x over previous
//
#include <hip/hip_runtime.h>
#include <cstddef>

#define HWO 16384   // 128*128
#define CTOT 1536

typedef __attribute__((ext_vector_type(8))) short bf16x8;
typedef __attribute__((ext_vector_type(4))) float f32x4;

__device__ inline unsigned short f2bf(float x) {
  union { float f; unsigned u; } v; v.f = x;
  unsigned r = v.u + 0x7FFFu + ((v.u >> 16) & 1u);
  return (unsigned short)(r >> 16);
}
__device__ inline float bf2f(unsigned short h) {
  union { unsigned u; float f; } v; v.u = ((unsigned)h) << 16; return v.f;
}

struct __align__(16) Prm { unsigned short i00, i01, i10, i11; float wx, wy; };

// ---------------------------------------------------------------------------
// Setup: 7 weight transposes + BN fold + mc1 + fuse_w LDS-tiled transpose.
// ---------------------------------------------------------------------------
struct SetupArgs {
  const float* W[7];
  unsigned short* T[7];
  int K[7], N[7], bstart[8];
  const float *bn_g, *bn_v, *bn_m, *bn_b;
  float *sc, *sh;
  const float* c1;
  float* mc1;                 // [2*96]
  const float* fw;            // fuse_w [1536][384]
  unsigned short* fwt;        // [384][1536] bf16
  int nTP;
};
__global__ __launch_bounds__(256) void setup_kernel(SetupArgs a) {
  int bid = blockIdx.x;
  if (bid < a.nTP) {
    int s = 0;
#pragma unroll
    for (int i = 1; i < 7; i++) if (bid >= a.bstart[i]) s = i;
    const int K = a.K[s], N = a.N[s];
    const int idx = (bid - a.bstart[s]) * 256 + threadIdx.x;
    if (idx >= K * N) return;
    const int k = idx / N, o = idx - k * N;
    a.T[s][(size_t)o * K + k] = f2bf(a.W[s][idx]);
    return;
  }
  bid -= a.nTP;
  if (bid < 2) {   // BN fold
    const int o = bid * 256 + threadIdx.x;
    if (o < 384) {
      const float sc = a.bn_g[o] * rsqrtf(a.bn_v[o] + 1e-5f);
      a.sc[o] = sc;
      a.sh[o] = a.bn_b[o] - a.bn_m[o] * sc;
    }
    return;
  }
  bid -= 2;
  if (bid < 192) {  // mc1: one block per (b*96+ch)
    const float4* p = (const float4*)(a.c1 + (size_t)bid * HWO);
    float acc = 0.f;
    for (int i = threadIdx.x; i < HWO / 4; i += 256) {
      const float4 v = p[i];
      acc += (v.x + v.y) + (v.z + v.w);
    }
    for (int o = 32; o > 0; o >>= 1) acc += __shfl_down(acc, o, 64);
    __shared__ float red[4];
    if ((threadIdx.x & 63) == 0) red[threadIdx.x >> 6] = acc;
    __syncthreads();
    if (threadIdx.x == 0)
      a.mc1[bid] = (red[0] + red[1] + red[2] + red[3]) * (1.0f / HWO);
    return;
  }
  bid -= 192;       // fuse_w transpose: 48 k-tiles x 12 o-tiles (32x32)
  const int tk = bid / 12, to = bid % 12;
  __shared__ float tile[32][33];
  const int rr0 = threadIdx.x >> 5, cch = threadIdx.x & 31;
#pragma unroll
  for (int rr = rr0; rr < 32; rr += 8)
    tile[rr][cch] = a.fw[(size_t)(tk * 32 + rr) * 384 + to * 32 + cch];
  __syncthreads();
#pragma unroll
  for (int rr = rr0; rr < 32; rr += 8)
    a.fwt[(size_t)(to * 32 + rr) * 1536 + tk * 32 + cch] = f2bf(tile[cch][rr]);
}

// ---------------------------------------------------------------------------
// Unified projection kernel: 4 segments (c4,c3,c2,c1), f32 [K][P] channel-major
// input, bf16 [P][384] output. BM=128, BN=192 (2 o-blocks), BK=32, 256 thr.
// ---------------------------------------------------------------------------
struct PSeg { const float* X; const unsigned short* Wt; const float* bias;
              unsigned short* Y; int P, K, blk0; };
struct PArgs { PSeg s[4]; };
__global__ __launch_bounds__(256) void proj_all(PArgs a) {
  int si = 0;
#pragma unroll
  for (int i = 1; i < 4; i++) if ((int)blockIdx.x >= a.s[i].blk0) si = i;
  const PSeg sg = a.s[si];
  const int rel = blockIdx.x - sg.blk0;
  const int pb = rel >> 1, ob = rel & 1;
  const int b = blockIdx.y;
  const int P = sg.P, K = sg.K;
  const int p0 = pb * 128;
  constexpr int LST = 40;
  __shared__ unsigned short Alds[128 * LST];
  __shared__ unsigned short Blds[192 * LST];
  const int tid = threadIdx.x;
  const int w = tid >> 6, lane = tid & 63;
  const int wm = w >> 1, wn = w & 1;
  const float* Xf = sg.X + (long)b * K * P;
  const unsigned short* Wt = sg.Wt;
  f32x4 acc[24];
#pragma unroll
  for (int i = 0; i < 24; i++) acc[i] = (f32x4){0.f, 0.f, 0.f, 0.f};
  const int lr = lane & 15, lk = (lane >> 4) * 8;

  for (int kc = 0; kc < K; kc += 32) {
    // A: 32 k x 128 pos (transpose-in-staging), 1024 tasks
#pragma unroll
    for (int it = 0; it < 4; it++) {
      const int idx = tid + it * 256;
      const int k = idx >> 5, pg = (idx & 31) * 4;
      const float4 v = *(const float4*)(Xf + (long)(kc + k) * P + p0 + pg);
      Alds[(pg + 0) * LST + k] = f2bf(v.x);
      Alds[(pg + 1) * LST + k] = f2bf(v.y);
      Alds[(pg + 2) * LST + k] = f2bf(v.z);
      Alds[(pg + 3) * LST + k] = f2bf(v.w);
    }
    // B: 192 rows x 32 k
#pragma unroll
    for (int it = 0; it < 3; it++) {
      const int idx = tid + it * 256;
      const int r = idx >> 2, ck = (idx & 3) * 8;
      *(uint4*)&Blds[r * LST + ck] =
          *(const uint4*)(Wt + (long)(ob * 192 + r) * K + kc + ck);
    }
    __syncthreads();
    bf16x8 af[4];
#pragma unroll
    for (int mt = 0; mt < 4; mt++)
      af[mt] = *(const bf16x8*)&Alds[((wm * 4 + mt) * 16 + lr) * LST + lk];
#pragma unroll
    for (int ot = 0; ot < 6; ot++) {
      const bf16x8 bfr = *(const bf16x8*)&Blds[((wn * 6 + ot) * 16 + lr) * LST + lk];
#pragma unroll
      for (int mt = 0; mt < 4; mt++)
        acc[mt * 6 + ot] = __builtin_amdgcn_mfma_f32_16x16x32_bf16(
            af[mt], bfr, acc[mt * 6 + ot], 0, 0, 0);
    }
    __syncthreads();
  }
  const int r0 = (lane >> 4) * 4;
#pragma unroll
  for (int mt = 0; mt < 4; mt++) {
#pragma unroll
    for (int ot = 0; ot < 6; ot++) {
      const int o = ob * 192 + (wn * 6 + ot) * 16 + lr;
      const float bv = sg.bias[o];
      const f32x4 r = acc[mt * 6 + ot];
#pragma unroll
      for (int jj = 0; jj < 4; jj++) {
        const long row = p0 + (wm * 4 + mt) * 16 + r0 + jj;
        sg.Y[((long)b * P + row) * 384 + o] = f2bf(r[jj] + bv);
      }
    }
  }
}

// ---------------------------------------------------------------------------
// Unified offset-conv kernel: 3 segments, bf16 [P][384] in, f32 [P][N] out.
// BM=128, BN-tile=128 (o-blocks per seg), K=384, BK=32, 256 thr.
// ---------------------------------------------------------------------------
struct OSeg { const unsigned short* X; const unsigned short* Wt;
              const float* bias; float* Y; int P, N, obn, blk0; };
struct OArgs { OSeg s[3]; };
__global__ __launch_bounds__(256) void offs_all(OArgs a) {
  int si = 0;
#pragma unroll
  for (int i = 1; i < 3; i++) if ((int)blockIdx.x >= a.s[i].blk0) si = i;
  const OSeg sg = a.s[si];
  const int rel = blockIdx.x - sg.blk0;
  const int pb = rel / sg.obn, ob = rel - pb * sg.obn;
  const int b = blockIdx.y;
  const int P = sg.P, N = sg.N;
  const int p0 = pb * 128, o0 = ob * 128;
  constexpr int LST = 40;
  __shared__ unsigned short Alds[128 * LST];
  __shared__ unsigned short Blds[128 * LST];
  const int tid = threadIdx.x;
  const int w = tid >> 6, lane = tid & 63;
  const int wm = w >> 1, wn = w & 1;
  const unsigned short* Xb = sg.X + (long)b * P * 384;
  f32x4 acc[16];
#pragma unroll
  for (int i = 0; i < 16; i++) acc[i] = (f32x4){0.f, 0.f, 0.f, 0.f};
  const int lr = lane & 15, lk = (lane >> 4) * 8;

  for (int kc = 0; kc < 384; kc += 32) {
#pragma unroll
    for (int it = 0; it < 2; it++) {
      const int idx = tid + it * 256;
      const int r = idx >> 2, ck = (idx & 3) * 8;
      *(uint4*)&Alds[r * LST + ck] =
          *(const uint4*)(Xb + (long)(p0 + r) * 384 + kc + ck);
    }
#pragma unroll
    for (int it = 0; it < 2; it++) {
      const int idx = tid + it * 256;
      const int r = idx >> 2, ck = (idx & 3) * 8;
      uint4 v = {0u, 0u, 0u, 0u};
      if (o0 + r < N)
        v = *(const uint4*)(sg.Wt + (long)(o0 + r) * 384 + kc + ck);
      *(uint4*)&Blds[r * LST + ck] = v;
    }
    __syncthreads();
    bf16x8 af[4];
#pragma unroll
    for (int mt = 0; mt < 4; mt++)
      af[mt] = *(const bf16x8*)&Alds[((wm * 4 + mt) * 16 + lr) * LST + lk];
#pragma unroll
    for (int ot = 0; ot < 4; ot++) {
      const bf16x8 bfr = *(const bf16x8*)&Blds[((wn * 4 + ot) * 16 + lr) * LST + lk];
#pragma unroll
      for (int mt = 0; mt < 4; mt++)
        acc[mt * 4 + ot] = __builtin_amdgcn_mfma_f32_16x16x32_bf16(
            af[mt], bfr, acc[mt * 4 + ot], 0, 0, 0);
    }
    __syncthreads();
  }
  const int r0 = (lane >> 4) * 4;
#pragma unroll
  for (int mt = 0; mt < 4; mt++) {
#pragma unroll
    for (int ot = 0; ot < 4; ot++) {
      const int o = o0 + (wn * 4 + ot) * 16 + lr;
      if (o < N) {
        const float bv = sg.bias[o];
        const f32x4 r = acc[mt * 4 + ot];
#pragma unroll
        for (int jj = 0; jj < 4; jj++) {
          const long row = p0 + (wm * 4 + mt) * 16 + r0 + jj;
          sg.Y[((long)b * P + row) * N + o] = r[jj] + bv;
        }
      }
    }
  }
}

// ---------------------------------------------------------------------------
// Merged params + mean-partials: grid (32 p-chunks of 512, 12 gp, 2 b).
// Phase A: compute Prm for 512 positions -> global prm + LDS.
// Phase B: per-channel mean partials from LDS prm.
// ---------------------------------------------------------------------------
__global__ __launch_bounds__(256) void pm_kernel(
    const float* __restrict__ bo4, const float* __restrict__ bo3,
    const float* __restrict__ bo2,
    const unsigned short* __restrict__ bp4, const unsigned short* __restrict__ bp3,
    const unsigned short* __restrict__ bp2,
    Prm* __restrict__ prm, float* __restrict__ part) {
  const int gp = blockIdx.y, b = blockIdx.z;
  const int lvl = gp >> 2, g = gp & 3;
  const float* bo; int ls, H, offC;
  const unsigned short* bpL; int HWs_;
  if (lvl == 0)      { bo = bo4; ls = 3; H = 16; offC = 512; bpL = bp4; HWs_ = 256; }
  else if (lvl == 1) { bo = bo3; ls = 2; H = 32; offC = 128; bpL = bp3; HWs_ = 1024; }
  else               { bo = bo2; ls = 1; H = 64; offC = 32;  bpL = bp2; HWs_ = 4096; }
  const int s = 1 << ls, ss = s * s, W = H;
  const int tid = threadIdx.x;
  __shared__ Prm Plds[512];

  // Phase A: params for this block's 512 positions
#pragma unroll
  for (int ii = 0; ii < 2; ii++) {
    const int li = tid + ii * 256;
    const int p = blockIdx.x * 512 + li;
    const int yo = p >> 7, xo = p & 127;
    const int h = yo >> ls, i = yo & (s - 1);
    const int w = xo >> ls, j = xo & (s - 1);
    const int sp = h * W + w;
    const float* offp = bo + ((size_t)b * (W * H) + sp) * offC;
    const float cx = offp[g * ss + i * s + j];
    const float cy = offp[(4 + g) * ss + i * s + j];
    const float inv_s = 1.0f / (float)s;
    const float offx = cx * 0.25f + ((float)j - (s - 1) * 0.5f) * inv_s;
    const float offy = cy * 0.25f + ((float)i - (s - 1) * 0.5f) * inv_s;
    float xf = fminf(fmaxf((float)w + offx, 0.0f), (float)(W - 1));
    float yf = fminf(fmaxf((float)h + offy, 0.0f), (float)(H - 1));
    const float x0f = floorf(xf), y0f = floorf(yf);
    const int x0 = (int)x0f, y0 = (int)y0f;
    const int x1 = min(x0 + 1, W - 1), y1 = min(y0 + 1, H - 1);
    Prm pr;
    pr.i00 = (unsigned short)(y0 * W + x0);
    pr.i01 = (unsigned short)(y0 * W + x1);
    pr.i10 = (unsigned short)(y1 * W + x0);
    pr.i11 = (unsigned short)(y1 * W + x1);
    pr.wx = xf - x0f;
    pr.wy = yf - y0f;
    prm[((size_t)b * 12 + gp) * HWO + p] = pr;
    Plds[li] = pr;
  }
  __syncthreads();

  // Phase B: mean partials (12 chunks x 21 lanes layout)
  const int chunk = tid % 12, pl = tid / 12;
  float acc[8];
#pragma unroll
  for (int j = 0; j < 8; j++) acc[j] = 0.f;
  const unsigned short* qb = bpL + (size_t)b * HWs_ * 384 + g * 96 + chunk * 8;
  if (tid < 252) {
    for (int it = 0; it < 25; it++) {
      const int pli = it * 21 + pl;
      if (pli < 512) {
        const Prm pr = Plds[pli];
        const float wx = pr.wx, wy = pr.wy;
        const float w00 = (1.f - wx) * (1.f - wy), w01 = wx * (1.f - wy);
        const float w10 = (1.f - wx) * wy, w11 = wx * wy;
        const uint4 v00 = *(const uint4*)(qb + (size_t)pr.i00 * 384);
        const uint4 v01 = *(const uint4*)(qb + (size_t)pr.i01 * 384);
        const uint4 v10 = *(const uint4*)(qb + (size_t)pr.i10 * 384);
        const uint4 v11 = *(const uint4*)(qb + (size_t)pr.i11 * 384);
        const unsigned short* s00 = (const unsigned short*)&v00;
        const unsigned short* s01 = (const unsigned short*)&v01;
        const unsigned short* s10 = (const unsigned short*)&v10;
        const unsigned short* s11 = (const unsigned short*)&v11;
#pragma unroll
        for (int j = 0; j < 8; j++)
          acc[j] += w00 * bf2f(s00[j]) + w01 * bf2f(s01[j]) +
                    w10 * bf2f(s10[j]) + w11 * bf2f(s11[j]);
      }
    }
  }
  __shared__ float red[12][8][22];
  if (tid < 252) {
#pragma unroll
    for (int j = 0; j < 8; j++) red[chunk][j][pl] = acc[j];
  }
  __syncthreads();
  if (tid < 96) {
    float sum = 0.f;
#pragma unroll
    for (int l = 0; l < 21; l++) sum += red[tid >> 3][tid & 7][l];
    part[((size_t)blockIdx.x * 2 + b) * 1152 + gp * 96 + tid] = sum;
  }
}

// ---------------------------------------------------------------------------
// SSM prep (mean from partials or mc1 path).
// ---------------------------------------------------------------------------
__global__ __launch_bounds__(64) void ssm_prep(
    const float* __restrict__ part, const float* __restrict__ mc1,
    const float* __restrict__ mlp1_w, const float* __restrict__ mlp1_b,
    const float* __restrict__ in_w, const float* __restrict__ in_b,
    const float* __restrict__ xproj_w, const float* __restrict__ dt_w,
    const float* __restrict__ dt_b, float* __restrict__ u_out,
    float2* __restrict__ dtdu_out, float* __restrict__ Bs_out,
    float* __restrict__ Cs_out) {
  const int bc = blockIdx.x;
  const int b = bc / 1536, c = bc - b * 1536;
  const int d = threadIdx.x;
  float sv;
  if (c < 1152) {
    float a = (d < 32) ? part[((size_t)d * 2 + b) * 1152 + c] : 0.f;
    a += __shfl_xor(a, 1, 64);  a += __shfl_xor(a, 2, 64);
    a += __shfl_xor(a, 4, 64);  a += __shfl_xor(a, 8, 64);
    a += __shfl_xor(a, 16, 64); a += __shfl_xor(a, 32, 64);
    sv = a * (1.0f / HWO);
  } else {
    const int c2 = c - 1152;
    float a = mc1[b * 96 + d] * mlp1_w[d * 384 + c2];
    if (d < 32) a += mc1[b * 96 + 64 + d] * mlp1_w[(64 + d) * 384 + c2];
    a += __shfl_xor(a, 1, 64);  a += __shfl_xor(a, 2, 64);
    a += __shfl_xor(a, 4, 64);  a += __shfl_xor(a, 8, 64);
    a += __shfl_xor(a, 16, 64); a += __shfl_xor(a, 32, 64);
    sv = a + mlp1_b[c2];
  }
  const float u = sv * in_w[d] + in_b[d];
  __shared__ float ush[64];
  __shared__ float proj[33];
  ush[d] = u;
  __syncthreads();
  if (d < 33) {
    float acc = 0.f;
    for (int k = 0; k < 64; k++) acc = fmaf(ush[k], xproj_w[k * 33 + d], acc);
    proj[d] = acc;
  }
  __syncthreads();
  float dtv = proj[0] * dt_w[d] + dt_b[d];
  dtv = (dtv > 20.0f) ? dtv : log1pf(__expf(dtv));   // softplus
  u_out[(size_t)bc * 64 + d] = u;
  dtdu_out[(size_t)bc * 64 + d] = make_float2(dtv, dtv * u);
  if (d < 16) {
    Bs_out[(size_t)bc * 16 + d] = proj[1 + d];
    Cs_out[(size_t)bc * 16 + d] = proj[17 + d];
  }
}

// ---------------------------------------------------------------------------
// Parallel associative scan. grid = (64 d, 2 dir, 2 b), block 256.
// ---------------------------------------------------------------------------
__global__ __launch_bounds__(256) void ssm_scan_par(
    const float2* __restrict__ dtdu, const float* __restrict__ Bs,
    const float* __restrict__ Cs, const float* __restrict__ A_log,
    float* __restrict__ y) {
  const int d = blockIdx.x, dir = blockIdx.y, b = blockIdx.z;
  const int t = threadIdx.x;
  const int j = t >> 4, n = t & 15;
  const float A = -__expf(A_log[d * 16 + n]);
  const int s0 = j * 96;
  const int c0 = dir ? (1535 - s0) : s0;
  const int step = dir ? -1 : 1;
  const float2* dbase = dtdu + (size_t)b * 1536 * 64 + (size_t)c0 * 64 + d;
  const float* bbase = Bs + (size_t)b * 1536 * 16 + (size_t)c0 * 16 + n;
  const float* cbase = Cs + (size_t)b * 1536 * 16 + (size_t)c0 * 16 + n;
  const long dstep = (long)step * 64;
  const long bstep = (long)step * 16;

  float Ap = 1.f, Bp = 0.f;
  {
    const float2* dp = dbase;
    const float* bp = bbase;
    float2 td = *dp;
    float Bv = *bp;
    for (int i = 0; i < 96; i++) {
      const float2 tdc = td;
      const float Bc = Bv;
      dp += dstep; bp += bstep;
      if (i + 1 < 96) { td = *dp; Bv = *bp; }
      const float a = __expf(tdc.x * A);
      Bp = fmaf(a, Bp, tdc.y * Bc);
      Ap *= a;
    }
  }
  __shared__ float sA[16][16], sB[16][16];
  sA[j][n] = Ap;
  sB[j][n] = Bp;
  __syncthreads();
  float H = 0.f;
  for (int jj = 0; jj < j; jj++) H = fmaf(sA[jj][n], H, sB[jj][n]);

  float* yb = y + (size_t)(b * 2 + dir) * 1536 * 64;
  {
    const float2* dp = dbase;
    const float* bp = bbase;
    const float* cp = cbase;
    float2 td = *dp;
    float Bv = *bp;
    float Cv = *cp;
    float h = H;
    int c = c0;
    for (int i = 0; i < 96; i++) {
      const float2 tdc = td;
      const float Bc = Bv, Cc = Cv;
      dp += dstep; bp += bstep; cp += bstep;
      if (i + 1 < 96) { td = *dp; Bv = *bp; Cv = *cp; }
      const float a = __expf(tdc.x * A);
      h = fmaf(a, h, tdc.y * Bc);
      float pr = h * Cc;
      pr += __shfl_xor(pr, 1, 64);
      pr += __shfl_xor(pr, 2, 64);
      pr += __shfl_xor(pr, 4, 64);
      pr += __shfl_xor(pr, 8, 64);
      if (n == 0) yb[(size_t)c * 64 + d] = pr;
      c += step;
    }
  }
}

// ---------------------------------------------------------------------------
// Gate.
// ---------------------------------------------------------------------------
__global__ __launch_bounds__(64) void gate_kernel(
    const float* __restrict__ y, const float* __restrict__ u,
    const float* __restrict__ Dp, const float* __restrict__ out_w,
    const float* __restrict__ out_b, float* __restrict__ gate) {
  const int c = blockIdx.x, b = blockIdx.y, d = threadIdx.x;
  const size_t i = ((size_t)b * 1536 + c) * 64 + d;
  float yt = y[((size_t)(b * 2) * 1536 + c) * 64 + d]
           + y[((size_t)(b * 2 + 1) * 1536 + c) * 64 + d]
           + Dp[d] * u[i];
  float v = yt * out_w[d];
  for (int o = 32; o > 0; o >>= 1) v += __shfl_down(v, o, 64);
  if (d == 0) gate[b * 1536 + c] = 1.0f / (1.0f + __expf(-(v + out_b[0])));
}

// ---------------------------------------------------------------------------
// wg[b][o][k] = wtf[o][k] * gate[b][k]  (coalesced, bf16; real div for k0).
// ---------------------------------------------------------------------------
__global__ __launch_bounds__(256) void gate_fold(
    const unsigned short* __restrict__ wtf, const float* __restrict__ gate,
    unsigned short* __restrict__ wg) {
  const int b = blockIdx.y;
  const int idx8 = blockIdx.x * 256 + threadIdx.x;   // 0..73727 (16B groups)
  const int o = idx8 / 192;
  const int k0 = (idx8 - o * 192) * 8;
  const size_t idx = (size_t)o * 1536 + k0;
  const uint4 v = *(const uint4*)(wtf + idx);
  const unsigned short* s = (const unsigned short*)&v;
  const float* g = gate + b * 1536 + k0;
  unsigned short r8[8];
#pragma unroll
  for (int j = 0; j < 8; j++) r8[j] = f2bf(bf2f(s[j]) * g[j]);
  *(uint4*)(wg + (size_t)b * 589824 + idx) = *(const uint4*)r8;
}

// ---------------------------------------------------------------------------
// Fuse GEMM v2: BM=128, BK=32, BN=384, 1024 threads (16 waves, 4x4).
// gp uniform per k-step (96 = 3*32): prm loaded once per gp (outer loop).
// LDS 41 KB -> 1 block/CU, 4 waves/SIMD. grid (128, 2).
// ---------------------------------------------------------------------------
__global__ __launch_bounds__(1024, 4) void fuse_gemm(
    const unsigned short* __restrict__ bp4, const unsigned short* __restrict__ bp3,
    const unsigned short* __restrict__ bp2, const unsigned short* __restrict__ bp1,
    const Prm* __restrict__ prm, const unsigned short* __restrict__ wg,
    const float* __restrict__ ep_a, const float* __restrict__ ep_b,
    unsigned short* __restrict__ hbf) {
  constexpr int LST = 40;
  __shared__ unsigned short Alds[128 * LST];   // 10240 B
  __shared__ unsigned short Blds[384 * LST];   // 30720 B
  const int tid = threadIdx.x;
  const int w = tid >> 6, lane = tid & 63;
  const int wm = w >> 2, wn = w & 3;           // 4 x 4 waves
  const int b = blockIdx.y;
  const int p0 = blockIdx.x * 128;
  const unsigned short* Wb = wg + (size_t)b * 589824;
  f32x4 acc[12];
#pragma unroll
  for (int i = 0; i < 12; i++) acc[i] = (f32x4){0.f, 0.f, 0.f, 0.f};
  const int lr = lane & 15, lk = (lane >> 4) * 8;
  const int ar = tid >> 2, ag = tid & 3;       // A-gather row / col-group (tid<512)

  for (int gp = 0; gp < 12; ++gp) {
    const int lvl = gp >> 2;
    const unsigned short* bpL; int HWs_;
    if (lvl == 0)      { bpL = bp4; HWs_ = 256; }
    else if (lvl == 1) { bpL = bp3; HWs_ = 1024; }
    else               { bpL = bp2; HWs_ = 4096; }
    Prm pr; pr.i00 = pr.i01 = pr.i10 = pr.i11 = 0; pr.wx = pr.wy = 0.f;
    if (tid < 512) pr = prm[((size_t)b * 12 + gp) * HWO + p0 + ar];
    const float wx = pr.wx, wy = pr.wy;
    const float w00 = (1.f - wx) * (1.f - wy), w01 = wx * (1.f - wy);
    const float w10 = (1.f - wx) * wy, w11 = wx * wy;
#pragma unroll
    for (int t3 = 0; t3 < 3; ++t3) {
      const int kc = gp * 96 + t3 * 32;
      if (tid < 512) {
        const int colL = (gp & 3) * 96 + t3 * 32 + ag * 8;
        const unsigned short* qb = bpL + (size_t)b * HWs_ * 384 + colL;
        const uint4 v00 = *(const uint4*)(qb + (size_t)pr.i00 * 384);
        const uint4 v01 = *(const uint4*)(qb + (size_t)pr.i01 * 384);
        const uint4 v10 = *(const uint4*)(qb + (size_t)pr.i10 * 384);
        const uint4 v11 = *(const uint4*)(qb + (size_t)pr.i11 * 384);
        const unsigned short* s00 = (const unsigned short*)&v00;
        const unsigned short* s01 = (const unsigned short*)&v01;
        const unsigned short* s10 = (const unsigned short*)&v10;
        const unsigned short* s11 = (const unsigned short*)&v11;
        unsigned short r8[8];
#pragma unroll
        for (int jj = 0; jj < 8; jj++)
          r8[jj] = f2bf(w00 * bf2f(s00[jj]) + w01 * bf2f(s01[jj]) +
                        w10 * bf2f(s10[jj]) + w11 * bf2f(s11[jj]));
        *(uint4*)&Alds[ar * LST + ag * 8] = *(const uint4*)r8;
      }
      // B stage: 1536 tasks over 1024 threads
      {
        const int r = tid >> 2, ck = (tid & 3) * 8;
        *(uint4*)&Blds[r * LST + ck] =
            *(const uint4*)(Wb + (size_t)r * 1536 + kc + ck);
      }
      if (tid >= 512) {
        const int idx = tid + 512;
        const int r = idx >> 2, ck = (idx & 3) * 8;
        *(uint4*)&Blds[r * LST + ck] =
            *(const uint4*)(Wb + (size_t)r * 1536 + kc + ck);
      }
      __syncthreads();
      bf16x8 af[2];
#pragma unroll
      for (int mt = 0; mt < 2; mt++)
        af[mt] = *(const bf16x8*)&Alds[((wm * 2 + mt) * 16 + lr) * LST + lk];
#pragma unroll
      for (int ot = 0; ot < 6; ot++) {
        const bf16x8 bfr = *(const bf16x8*)&Blds[((wn * 6 + ot) * 16 + lr) * LST + lk];
#pragma unroll
        for (int mt = 0; mt < 2; mt++)
          acc[mt * 6 + ot] = __builtin_amdgcn_mfma_f32_16x16x32_bf16(
              af[mt], bfr, acc[mt * 6 + ot], 0, 0, 0);
      }
      __syncthreads();
    }
  }
  // bp1 (c1) block: direct copy staging
  for (int kc = 1152; kc < 1536; kc += 32) {
    if (tid < 512)
      *(uint4*)&Alds[ar * LST + ag * 8] =
          *(const uint4*)(bp1 + ((size_t)b * HWO + p0 + ar) * 384 +
                          (kc - 1152) + ag * 8);
    {
      const int r = tid >> 2, ck = (tid & 3) * 8;
      *(uint4*)&Blds[r * LST + ck] =
          *(const uint4*)(Wb + (size_t)r * 1536 + kc + ck);
    }
    if (tid >= 512) {
      const int idx = tid + 512;
      const int r = idx >> 2, ck = (idx & 3) * 8;
      *(uint4*)&Blds[r * LST + ck] =
          *(const uint4*)(Wb + (size_t)r * 1536 + kc + ck);
    }
    __syncthreads();
    bf16x8 af[2];
#pragma unroll
    for (int mt = 0; mt < 2; mt++)
      af[mt] = *(const bf16x8*)&Alds[((wm * 2 + mt) * 16 + lr) * LST + lk];
#pragma unroll
    for (int ot = 0; ot < 6; ot++) {
      const bf16x8 bfr = *(const bf16x8*)&Blds[((wn * 6 + ot) * 16 + lr) * LST + lk];
#pragma unroll
      for (int mt = 0; mt < 2; mt++)
        acc[mt * 6 + ot] = __builtin_amdgcn_mfma_f32_16x16x32_bf16(
            af[mt], bfr, acc[mt * 6 + ot], 0, 0, 0);
    }
    __syncthreads();
  }
  // epilogue: BN + ReLU -> bf16 hbf [p][384]
  const int r0 = (lane >> 4) * 4;
#pragma unroll
  for (int mt = 0; mt < 2; mt++) {
#pragma unroll
    for (int ot = 0; ot < 6; ot++) {
      const int o = (wn * 6 + ot) * 16 + lr;
      const float sa = ep_a[o], sb = ep_b[o];
      const f32x4 r = acc[mt * 6 + ot];
#pragma unroll
      for (int jj = 0; jj < 4; jj++) {
        const size_t row = p0 + (wm * 2 + mt) * 16 + r0 + jj;
        hbf[((size_t)b * HWO + row) * 384 + o] =
            f2bf(fmaxf(fmaf(r[jj], sa, sb), 0.f));
      }
    }
  }
}

// ---------------------------------------------------------------------------
// Heads (position-major h).
// ---------------------------------------------------------------------------
__global__ __launch_bounds__(256) void head_pm(
    const unsigned short* __restrict__ h,
    const float* __restrict__ pred_w, const float* __restrict__ pred_b,
    const float* __restrict__ bird_w, const float* __restrict__ bird_b,
    float* __restrict__ out) {
  const int idx = blockIdx.x * 256 + threadIdx.x;
  const int b = idx >> 14, p = idx & 16383;
  const unsigned short* hb = h + ((size_t)b * HWO + p) * 384;
  float a0 = pred_b[0], a1 = pred_b[1], a2 = pred_b[2];
  float a3 = pred_b[3], a4 = pred_b[4], a5 = pred_b[5];
  float a6 = bird_b[0], a7 = bird_b[1];
  for (int c8 = 0; c8 < 384; c8 += 8) {
    const uint4 v = *(const uint4*)(hb + c8);
    const unsigned short* sv = (const unsigned short*)&v;
#pragma unroll
    for (int jj = 0; jj < 8; jj++) {
      const int o = c8 + jj;
      const float hv = bf2f(sv[jj]);
      const float* pw = pred_w + o * 6;
      a0 = fmaf(hv, pw[0], a0);
      a1 = fmaf(hv, pw[1], a1);
      a2 = fmaf(hv, pw[2], a2);
      a3 = fmaf(hv, pw[3], a3);
      a4 = fmaf(hv, pw[4], a4);
      a5 = fmaf(hv, pw[5], a5);
      a6 = fmaf(hv, bird_w[o * 2 + 0], a6);
      a7 = fmaf(hv, bird_w[o * 2 + 1], a7);
    }
  }
  float* ob = out + (size_t)b * 6 * HWO + p;
  ob[0] = a0; ob[HWO] = a1; ob[2 * HWO] = a2;
  ob[3 * HWO] = a3; ob[4 * HWO] = a4; ob[5 * HWO] = a5;
  float* ab = out + (size_t)12 * HWO + (size_t)b * 2 * HWO + p;
  ab[0] = a6; ab[HWO] = a7;
}

// ---------------------------------------------------------------------------
extern "C" void kernel_launch(void* const* d_in, const int* in_sizes, int n_in,
                              void* d_out, int out_size, void* d_ws, size_t ws_size,
                              hipStream_t stream) {
  const float* c1      = (const float*)d_in[0];
  const float* c2      = (const float*)d_in[1];
  const float* c3      = (const float*)d_in[2];
  const float* c4      = (const float*)d_in[3];
  const float* mlp1_w  = (const float*)d_in[4];
  const float* mlp1_b  = (const float*)d_in[5];
  const float* mlp2_w  = (const float*)d_in[6];
  const float* mlp2_b  = (const float*)d_in[7];
  const float* mlp3_w  = (const float*)d_in[8];
  const float* mlp3_b  = (const float*)d_in[9];
  const float* mlp4_w  = (const float*)d_in[10];
  const float* mlp4_b  = (const float*)d_in[11];
  const float* up2_w   = (const float*)d_in[12];
  const float* up2_b   = (const float*)d_in[13];
  const float* up4_w   = (const float*)d_in[14];
  const float* up4_b   = (const float*)d_in[15];
  const float* up8_w   = (const float*)d_in[16];
  const float* up8_b   = (const float*)d_in[17];
  const float* ssm_in_w    = (const float*)d_in[18];
  const float* ssm_in_b    = (const float*)d_in[19];
  const float* ssm_xproj_w = (const float*)d_in[20];
  const float* ssm_dt_w    = (const float*)d_in[21];
  const float* ssm_dt_b    = (const float*)d_in[22];
  const float* ssm_A_log   = (const float*)d_in[23];
  const float* ssm_D       = (const float*)d_in[24];
  const float* ssm_out_w   = (const float*)d_in[25];
  const float* ssm_out_b   = (const float*)d_in[26];
  const float* fuse_w  = (const float*)d_in[27];
  const float* bn_g    = (const float*)d_in[28];
  const float* bn_b    = (const float*)d_in[29];
  const float* bn_m    = (const float*)d_in[30];
  const float* bn_v    = (const float*)d_in[31];
  const float* pred_w  = (const float*)d_in[32];
  const float* pred_b  = (const float*)d_in[33];
  const float* bird_w  = (const float*)d_in[34];
  const float* bird_b  = (const float*)d_in[35];
  float* outp = (float*)d_out;
  (void)in_sizes; (void)n_in; (void)out_size; (void)ws_size;

  float* ws = (float*)d_ws;
  size_t off = 0;
  auto alloc = [&](size_t n) { float* p = ws + off; off += n; return p; };
  // alloc() counts FLOATS; bf16 [2][16384][384] = 6291456 floats.
  unsigned short* bp1 = (unsigned short*)alloc(6291456);   // bf16 [2][16384][384]
  unsigned short* bp4 = (unsigned short*)alloc(98304);     // bf16 [2][256][384]
  unsigned short* bp3 = (unsigned short*)alloc(393216);    // bf16 [2][1024][384]
  unsigned short* bp2 = (unsigned short*)alloc(1572864);   // bf16 [2][4096][384]
  float* bo4 = alloc(262144);                              // f32 [2][256][512]
  float* bo3 = alloc(262144);                              // f32 [2][1024][128]
  float* bo2 = alloc(262144);                              // f32 [2][4096][32]
  Prm* prm = (Prm*)alloc(1572864);                         // [2][12][16384] x16B
  float* part = alloc(73728);                              // [32][2][1152]
  float* mc1  = alloc(192);
  float* ub   = alloc(196608);
  float2* dtdu = (float2*)alloc(393216);
  float* Bsb  = alloc(49152);
  float* Csb  = alloc(49152);
  float* yb   = alloc(393216);
  float* gteb = alloc(3072);
  float* scb  = alloc(384);
  float* shb  = alloc(384);
  unsigned short* hbf = (unsigned short*)alloc(6291456);   // bf16 [2][16384][384]
  unsigned short* t1  = (unsigned short*)(ws + off);
  unsigned short* t2  = t1 + 36864;
  unsigned short* t3  = t2 + 36864;
  unsigned short* t4  = t3 + 73728;
  unsigned short* t8  = t4 + 147456;
  unsigned short* t4u = t8 + 196608;
  unsigned short* t2u = t4u + 49152;
  unsigned short* wtf = t2u + 12288;        // bf16 [384][1536]
  unsigned short* wg  = wtf + 589824;       // bf16 [2][384][1536]

  // 0) setup: transposes + BN fold + mc1 + fuse_w transpose
  {
    SetupArgs sp;
    const float* Ws[7] = {mlp1_w, mlp2_w, mlp3_w, mlp4_w, up8_w, up4_w, up2_w};
    unsigned short* Ts[7] = {t1, t2, t3, t4, t8, t4u, t2u};
    const int Ks[7] = {96, 96, 192, 384, 384, 384, 384};
    const int Ns[7] = {384, 384, 384, 384, 512, 128, 32};
    int bs = 0;
    for (int i = 0; i < 7; i++) {
      sp.W[i] = Ws[i]; sp.T[i] = Ts[i]; sp.K[i] = Ks[i]; sp.N[i] = Ns[i];
      sp.bstart[i] = bs;
      bs += (Ks[i] * Ns[i] + 255) / 256;
    }
    sp.bstart[7] = bs;
    sp.nTP = bs;
    sp.bn_g = bn_g; sp.bn_v = bn_v; sp.bn_m = bn_m; sp.bn_b = bn_b;
    sp.sc = scb; sp.sh = shb;
    sp.c1 = c1; sp.mc1 = mc1;
    sp.fw = fuse_w; sp.fwt = wtf;
    hipLaunchKernelGGL(setup_kernel, dim3(bs + 2 + 192 + 576), dim3(256), 0, stream, sp);
  }

  // 1) all 4 projections in one launch (340 blocks x 2 batches)
  {
    PArgs pa;
    pa.s[0] = {c4, t4, mlp4_b, bp4, 256, 384, 0};
    pa.s[1] = {c3, t3, mlp3_b, bp3, 1024, 192, 4};
    pa.s[2] = {c2, t2, mlp2_b, bp2, 4096, 96, 20};
    pa.s[3] = {c1, t1, mlp1_b, bp1, 16384, 96, 84};
    hipLaunchKernelGGL(proj_all, dim3(340, 2), dim3(256), 0, stream, pa);
  }
  // 2) all 3 offset convs in one launch (48 blocks x 2 batches)
  {
    OArgs oa;
    oa.s[0] = {bp4, t8, up8_b, bo4, 256, 512, 4, 0};
    oa.s[1] = {bp3, t4u, up4_b, bo3, 1024, 128, 1, 8};
    oa.s[2] = {bp2, t2u, up2_b, bo2, 4096, 32, 1, 16};
    hipLaunchKernelGGL(offs_all, dim3(48, 2), dim3(256), 0, stream, oa);
  }
  // 3) params + mean partials (merged)
  hipLaunchKernelGGL(pm_kernel, dim3(32, 12, 2), dim3(256), 0, stream,
                     bo4, bo3, bo2, bp4, bp3, bp2, prm, part);
  // 4) ssm prep + parallel scan + gate
  hipLaunchKernelGGL(ssm_prep, dim3(3072), dim3(64), 0, stream,
                     part, mc1, mlp1_w, mlp1_b, ssm_in_w, ssm_in_b,
                     ssm_xproj_w, ssm_dt_w, ssm_dt_b, ub, dtdu, Bsb, Csb);
  hipLaunchKernelGGL(ssm_scan_par, dim3(64, 2, 2), dim3(256), 0, stream,
                     dtdu, Bsb, Csb, ssm_A_log, yb);
  hipLaunchKernelGGL(gate_kernel, dim3(1536, 2), dim3(64), 0, stream,
                     yb, ub, ssm_D, ssm_out_w, ssm_out_b, gteb);
  // 5) per-batch gated weights
  hipLaunchKernelGGL(gate_fold, dim3(288, 2), dim3(256), 0, stream, wtf, gteb, wg);
  // 6) fused gather-GEMM v2 + BN + ReLU -> hbf
  hipLaunchKernelGGL(fuse_gemm, dim3(128, 2), dim3(1024), 0, stream,
                     bp4, bp3, bp2, bp1, prm, wg, scb, shb, hbf);
  // 7) heads
  hipLaunchKernelGGL(head_pm, dim3(128), dim3(256), 0, stream,
                     hbf, pred_w, pred_b, bird_w, bird_b, outp);
}